// Round 12
// baseline (204.628 us; speedup 1.0000x reference)
//
#include <hip/hip_runtime.h>
#include <math.h>

#define HEADS 8
#define DKEY 64
#define DVAL 192
#define SEQ 2048
#define DIMM 1536
#define NREL 192
#define NB 32
#define TDIST (2*SEQ-1)   // 4095

typedef __attribute__((ext_vector_type(8))) short short8v;   // bf16x8 MFMA frag
typedef __attribute__((ext_vector_type(4))) float f32x4;
typedef __attribute__((ext_vector_type(4))) unsigned short ushort4v;

__device__ __forceinline__ unsigned short f2bf(float f) {
    unsigned int u = __float_as_uint(f);
    u += 0x7FFFu + ((u >> 16) & 1u);          // RNE
    return (unsigned short)(u >> 16);
}
__device__ __forceinline__ float bf2f(unsigned short h) {
    return __uint_as_float(((unsigned int)h) << 16);
}

#define GLOAD16(gp, lp) __builtin_amdgcn_global_load_lds( \
    (const __attribute__((address_space(1))) void*)(gp),  \
    (__attribute__((address_space(3))) void*)(lp), 16, 0, 0)

// ---------------------------------------------------------------------------
// Positional embedding -> bf16 [4096][192]; row 4095 zeroed. All f32.
// ---------------------------------------------------------------------------
__global__ __launch_bounds__(256) void pos_embed_kernel(unsigned short* __restrict__ posb) {
    const int tid = threadIdx.x;
    const int f = tid & 31;
    const int t = blockIdx.x * 8 + (tid >> 5);    // 0..4095
    unsigned short* row = posb + (size_t)t * NREL;
    if (t >= TDIST) {             // pad row: zeros
        row[f] = 0; row[NB+f] = 0; row[2*NB+f] = 0;
        row[96+f] = 0; row[96+NB+f] = 0; row[96+2*NB+f] = 0;
        return;
    }
    float dist = (float)(t - (SEQ - 1));
    float absd = fabsf(dist);
    float sgn  = (dist > 0.0f) ? 1.0f : ((dist < 0.0f) ? -1.0f : 0.0f);
    float hl = exp2f(3.0f + 8.0f * (float)f / 31.0f);
    float e = exp2f(-absd / hl);
    float cw = exp2f((float)(f + 1)) - 1.0f;
    float c = (cw > absd) ? 1.0f : 0.0f;
    // xlogy(conc-1, absd): first arg > 0 always, so absd==0 gives -inf
    float conc = (float)(4 * (f + 1) * (f + 1));
    float rate = ((float)(f + 1)) / 16.0f;
    float lu = (absd > 0.0f)
        ? ((conc - 1.0f) * logf(absd) - rate * absd)
        : -INFINITY;
    float ln = lgammaf(conc) - conc * logf(rate);
    float g = expf(lu - ln) + 1e-8f;
    float gm = g;
    #pragma unroll
    for (int off = 16; off >= 1; off >>= 1)
        gm = fmaxf(gm, __shfl_xor(gm, off, 32));
    g = g / gm;
    row[f]           = f2bf(e);
    row[NB + f]      = f2bf(c);
    row[2*NB + f]    = f2bf(g);
    row[96 + f]      = f2bf(sgn * e);
    row[96 + NB + f] = f2bf(sgn * c);
    row[96 + 2*NB+f] = f2bf(sgn * g);
}

// ---------------------------------------------------------------------------
// x f32 -> bf16 (plain)
// ---------------------------------------------------------------------------
__global__ __launch_bounds__(256) void cast_bf16(
    const float4* __restrict__ in, ushort4v* __restrict__ hi, int n4)
{
    int i = blockIdx.x * 256 + threadIdx.x;
    if (i >= n4) return;
    float4 v = in[i];
    hi[i] = (ushort4v){ f2bf(v.x), f2bf(v.y), f2bf(v.z), f2bf(v.w) };
}

// ---------------------------------------------------------------------------
// W f32 [R][C] -> bf16 transposed [C][R], optionally pre-scaled.
// ---------------------------------------------------------------------------
__global__ __launch_bounds__(256) void castT_kernel(
    const float* __restrict__ in, unsigned short* __restrict__ hiT,
    int R, int C, float scale)
{
    __shared__ float t[32][33];
    int c0 = blockIdx.x * 32, r0 = blockIdx.y * 32;
    int tx = threadIdx.x & 31, ty = threadIdx.x >> 5;
    #pragma unroll
    for (int rr = ty; rr < 32; rr += 8)
        t[rr][tx] = in[(size_t)(r0 + rr) * C + c0 + tx] * scale;
    __syncthreads();
    #pragma unroll
    for (int cc = ty; cc < 32; cc += 8)
        hiT[(size_t)(c0 + cc) * R + r0 + tx] = f2bf(t[tx][cc]);
}

// ---------------------------------------------------------------------------
// bf16 MFMA GEMM, 128x64 tile, double-buffered. 4 waves = 2x2 of (64m x 32n).
//  MODE 0: C f32 [M][N] (+bias)
//  MODE 2: O bf16 per-head [8][4096][64]  (relb; col = h*64+d)
// ---------------------------------------------------------------------------
template<int MODE>
__global__ __launch_bounds__(256) void gemm_bf16_t(
    const unsigned short* __restrict__ A, const unsigned short* __restrict__ Bt,
    float* __restrict__ C, const float* __restrict__ bias,
    unsigned short* __restrict__ O,
    int M, int N, int K)
{
    __shared__ unsigned short A0[128*32], A1[128*32];
    __shared__ unsigned short B0[64*32],  B1[64*32];
    const int tid  = threadIdx.x;
    const int lane = tid & 63;
    const int wave = tid >> 6;
    const int wr = (wave >> 1) * 64, wc = (wave & 1) * 32;
    const int m0 = blockIdx.y * 128, n0 = blockIdx.x * 64;

    const int sr = tid >> 2;
    const int sc = ((tid & 3) ^ ((tid >> 4) & 3)) * 8;
    const unsigned short* gA = A  + (size_t)(m0 + sr) * K + sc;
    const unsigned short* gB = Bt + (size_t)(n0 + sr) * K + sc;

    const int frow = lane & 15;
    const int rchunk = (((lane >> 4) ^ ((frow >> 2) & 3))) * 8;

    f32x4 acc[4][2] = {};
    const int nk = K >> 5;

    auto STAGE = [&](int k0, unsigned short* LA, unsigned short* LB) {
        GLOAD16(gA + k0, LA + (wave*16)*32);
        GLOAD16(gA + k0 + (size_t)64 * K, LA + (64 + wave*16)*32);
        GLOAD16(gB + k0, LB + (wave*16)*32);
    };

    STAGE(0, A0, B0);
    __syncthreads();

    for (int kt = 0; kt < nk; ++kt) {
        const unsigned short* LA = (kt & 1) ? A1 : A0;
        const unsigned short* LB = (kt & 1) ? B1 : B0;
        if (kt + 1 < nk)
            STAGE((kt + 1) << 5, (kt & 1) ? A0 : A1, (kt & 1) ? B0 : B1);
        short8v af[4], bf[2];
        #pragma unroll
        for (int mf = 0; mf < 4; ++mf)
            af[mf] = *(const short8v*)&LA[(wr + mf*16 + frow) * 32 + rchunk];
        #pragma unroll
        for (int nf = 0; nf < 2; ++nf)
            bf[nf] = *(const short8v*)&LB[(wc + nf*16 + frow) * 32 + rchunk];
        #pragma unroll
        for (int mf = 0; mf < 4; ++mf)
            #pragma unroll
            for (int nf = 0; nf < 2; ++nf)
                acc[mf][nf] = __builtin_amdgcn_mfma_f32_16x16x32_bf16(
                    af[mf], bf[nf], acc[mf][nf], 0, 0, 0);
        __syncthreads();
    }

    const int er = ((lane >> 4) << 2);
    const int ec = lane & 15;
    #pragma unroll
    for (int nf = 0; nf < 2; ++nf) {
        const int col = n0 + wc + nf*16 + ec;
        float bv = 0.0f;
        if (MODE == 0 && bias) bv = bias[col];
        #pragma unroll
        for (int mf = 0; mf < 4; ++mf) {
            const int row = m0 + wr + mf*16 + er;
            if (MODE == 0) {
                #pragma unroll
                for (int r = 0; r < 4; ++r)
                    C[(size_t)(row + r) * N + col] = acc[mf][nf][r] + bv;
            } else {
                const int hh = col >> 6, d = col & 63;
                #pragma unroll
                for (int r = 0; r < 4; ++r)
                    O[((size_t)hh*4096 + row + r)*64 + d] = f2bf(acc[mf][nf][r]);
            }
        }
    }
}

// ---------------------------------------------------------------------------
// Fused QKV GEMM — uniform plain bf16 now (q-split dropped; logit error
// ~0.007, measured-equivalent to the k-drop). 128x64 tile, double-buffered,
// grid (40,16). Epilogue: q -> qchi(+cbias)/qpb(+pbias), k -> khi, v -> vt^T.
// ---------------------------------------------------------------------------
__global__ __launch_bounds__(256) void gemm_qkv(
    const unsigned short* __restrict__ A, const unsigned short* __restrict__ Bt,
    const float* __restrict__ cbias, const float* __restrict__ pbias,
    unsigned short* __restrict__ qchi, unsigned short* __restrict__ qpb,
    unsigned short* __restrict__ khi,  unsigned short* __restrict__ vt,
    int M, int K)
{
    __shared__ unsigned short A0[128*32], A1[128*32];
    __shared__ unsigned short B0[64*32],  B1[64*32];
    const int tid  = threadIdx.x;
    const int lane = tid & 63;
    const int wave = tid >> 6;
    const int wr = (wave >> 1) * 64, wc = (wave & 1) * 32;
    const int m0 = blockIdx.y * 128, n0 = blockIdx.x * 64;

    const int sr = tid >> 2;
    const int sc = ((tid & 3) ^ ((tid >> 4) & 3)) * 8;
    const unsigned short* gA = A  + (size_t)(m0 + sr) * K + sc;
    const unsigned short* gB = Bt + (size_t)(n0 + sr) * K + sc;

    const int frow = lane & 15;
    const int rchunk = (((lane >> 4) ^ ((frow >> 2) & 3))) * 8;

    f32x4 acc[4][2] = {};
    const int nk = K >> 5;

    auto STAGE = [&](int k0, unsigned short* LA, unsigned short* LB) {
        GLOAD16(gA + k0, LA + (wave*16)*32);
        GLOAD16(gA + k0 + (size_t)64 * K, LA + (64 + wave*16)*32);
        GLOAD16(gB + k0, LB + (wave*16)*32);
    };

    STAGE(0, A0, B0);
    __syncthreads();

    for (int kt = 0; kt < nk; ++kt) {
        const unsigned short* LA = (kt & 1) ? A1 : A0;
        const unsigned short* LB = (kt & 1) ? B1 : B0;
        if (kt + 1 < nk)
            STAGE((kt + 1) << 5, (kt & 1) ? A0 : A1, (kt & 1) ? B0 : B1);
        short8v af[4], bf[2];
        #pragma unroll
        for (int mf = 0; mf < 4; ++mf)
            af[mf] = *(const short8v*)&LA[(wr + mf*16 + frow) * 32 + rchunk];
        #pragma unroll
        for (int nf = 0; nf < 2; ++nf)
            bf[nf] = *(const short8v*)&LB[(wc + nf*16 + frow) * 32 + rchunk];
        #pragma unroll
        for (int mf = 0; mf < 4; ++mf)
            #pragma unroll
            for (int nf = 0; nf < 2; ++nf)
                acc[mf][nf] = __builtin_amdgcn_mfma_f32_16x16x32_bf16(
                    af[mf], bf[nf], acc[mf][nf], 0, 0, 0);
        __syncthreads();
    }

    const int er = ((lane >> 4) << 2);
    const int ec = lane & 15;
    #pragma unroll
    for (int nf = 0; nf < 2; ++nf) {
        const int col = n0 + wc + nf*16 + ec;
        if (col < 1024) {
            const bool isq = col < 512;
            const int hh = (col >> 6) & 7;
            const int d  = col & 63;
            const float cb = isq ? cbias[hh*64 + d] : 0.0f;
            const float pb = isq ? pbias[hh*64 + d] : 0.0f;
            #pragma unroll
            for (int mf = 0; mf < 4; ++mf) {
                const int row = m0 + wr + mf*16 + er;
                #pragma unroll
                for (int r = 0; r < 4; ++r) {
                    const float v = acc[mf][nf][r];
                    const size_t oi = ((size_t)hh*2048 + row + r)*64 + d;
                    if (isq) {
                        qchi[oi] = f2bf(v + cb);
                        qpb[oi]  = f2bf(v + pb);
                    } else {
                        khi[oi] = f2bf(v);
                    }
                }
            }
        } else {
            const int vc = col - 1024;
            #pragma unroll
            for (int mf = 0; mf < 4; ++mf) {
                const int row = m0 + wr + mf*16 + er;
                ushort4v pk;
                #pragma unroll
                for (int r = 0; r < 4; ++r) pk[r] = f2bf(acc[mf][nf][r]);
                *(ushort4v*)(vt + (size_t)vc * M + row) = pk;
            }
        }
    }
}

// ---------------------------------------------------------------------------
// MFMA flash attention v7 — plain-bf16 q & K; V direct global->VGPR with
// asm-pin before the phase barrier (rule #17: prevents the compiler sinking
// the loads to their uses, which was r10's regression). L2 latency hides
// under the S-phase. K/rel single-buffer 2-phase as r11. LDS 24 KB.
// Fixed-max softmax; exact wj-merge (bf16 scratch reusing srel).
// ---------------------------------------------------------------------------
#define QB 32
#define KB 64
#define FMAX 24.0f

__global__ __launch_bounds__(256, 2) void attn_mfma(
    const unsigned short* __restrict__ qchi,  // [8][2048][64]
    const unsigned short* __restrict__ qpb,
    const unsigned short* __restrict__ kghi,  // [8][2048][64]
    const unsigned short* __restrict__ vtg,   // [1536][2048] = [8][192][2048]
    const unsigned short* __restrict__ relb,  // [8][4096][64]
    unsigned short* __restrict__ o)           // [2048][1536] bf16
{
    __shared__ __align__(16) unsigned short skhi[64*64];    //  8 KB
    __shared__ __align__(16) unsigned short srel[96*64];    // 12 KB
    __shared__ __align__(16) unsigned short sP  [4*512];    //  4 KB
    // total 24 KB

    const int tid = threadIdx.x;
    const int h  = blockIdx.x & 7;
    const int i0 = (blockIdx.x >> 3) * QB;
    const int lane = tid & 63;
    const int wave = tid >> 6;
    const int wq = wave >> 1, wj = wave & 1;
    const int l15 = lane & 15, lg = lane >> 4;

    const size_t qrow = ((size_t)h*2048 + i0 + wq*16 + l15) * 64;
    short8v fqh[2], fqp[2];
    #pragma unroll
    for (int kh = 0; kh < 2; ++kh) {
        fqh[kh] = *(const short8v*)(qchi + qrow + kh*32 + lg*8);
        fqp[kh] = *(const short8v*)(qpb  + qrow + kh*32 + lg*8);
    }

    short8v onesf;
    #pragma unroll
    for (int j = 0; j < 8; ++j) onesf[j] = (short)0x3F80;

    f32x4 acc[12] = {};
    f32x4 acc_l = {};

    const int offw = wj*32 - wq*16 + 16;

    auto STAGE_K = [&](int t) {
        const size_t kbase = ((size_t)h*2048 + t*64) * 64;
        #pragma unroll
        for (int it = 0; it < 2; ++it) {
            int u = it*256 + tid; int row = u >> 3; int sch = (u & 7) ^ (row & 7);
            GLOAD16(kghi + kbase + row*64 + sch*8, &skhi[(it*256 + wave*64)*8]);
        }
    };
    auto STAGE_REL = [&](int t) {
        const size_t rbase = ((size_t)h*4096 + (t*64 - i0 + 2016)) * 64;
        #pragma unroll
        for (int it = 0; it < 3; ++it) {
            int u = it*256 + tid; int row = u >> 3; int sch = (u & 7) ^ (row & 7);
            GLOAD16(relb + rbase + row*64 + sch*8, &srel[(it*256 + wave*64)*8]);
        }
    };

    STAGE_K(0); STAGE_REL(0);
    __syncthreads();

    for (int t = 0; t < 32; ++t) {
        // ======== phase A: S(t) ========
        // 1. V fragments direct global->VGPR, issued FIRST (L2 latency hides
        //    under the whole S-phase); pinned materialized before the barrier.
        short8v fv[12];
        const int jw = t*64 + wj*32;
        #pragma unroll
        for (int nf = 0; nf < 12; ++nf)
            fv[nf] = *(const short8v*)(vtg +
                ((size_t)h*192 + nf*16 + l15)*2048 + jw + lg*8);
        // 2. ds_read K/rel fragments
        short8v bh[2][2], br[3][2];
        #pragma unroll
        for (int nf = 0; nf < 2; ++nf) {
            int jr = wj*32 + nf*16 + l15;
            #pragma unroll
            for (int kh = 0; kh < 2; ++kh) {
                int c = (kh*4 + lg) ^ (jr & 7);
                bh[nf][kh] = *(const short8v*)&skhi[jr*64 + c*8];
            }
        }
        #pragma unroll
        for (int cf = 0; cf < 3; ++cf) {
            int rr = offw + cf*16 + l15;
            #pragma unroll
            for (int kh = 0; kh < 2; ++kh) {
                int c = (kh*4 + lg) ^ (rr & 7);
                br[cf][kh] = *(const short8v*)&srel[rr*64 + c*8];
            }
        }
        // 3. content logits qh.kh (4 MFMA)
        f32x4 sc[2] = {};
        #pragma unroll
        for (int nf = 0; nf < 2; ++nf)
            #pragma unroll
            for (int kh = 0; kh < 2; ++kh)
                sc[nf] = __builtin_amdgcn_mfma_f32_16x16x32_bf16(fqh[kh], bh[nf][kh], sc[nf],0,0,0);
        // rel band logits (6 MFMA)
        f32x4 R[3] = {};
        #pragma unroll
        for (int cf = 0; cf < 3; ++cf)
            #pragma unroll
            for (int kh = 0; kh < 2; ++kh)
                R[cf] = __builtin_amdgcn_mfma_f32_16x16x32_bf16(fqp[kh], br[cf][kh], R[cf],0,0,0);
        // 4. diagonal gather
        float S[2][4];
        #pragma unroll
        for (int r = 0; r < 4; ++r) {
            int m = lg*4 + r;
            int tt = l15 + 15 - m;                // 0..30
            int idx = (((lane & 48) | (tt & 15))) << 2;
            float g0 = __uint_as_float((unsigned)__builtin_amdgcn_ds_bpermute(idx, (int)__float_as_uint(R[0][r])));
            float g1 = __uint_as_float((unsigned)__builtin_amdgcn_ds_bpermute(idx, (int)__float_as_uint(R[1][r])));
            float g2 = __uint_as_float((unsigned)__builtin_amdgcn_ds_bpermute(idx, (int)__float_as_uint(R[2][r])));
            bool cross = (tt >= 16);
            S[0][r] = sc[0][r] + (cross ? g1 : g0);
            S[1][r] = sc[1][r] + (cross ? g2 : g1);
        }
        // 5. fixed-max exponentials
        float p[2][4];
        #pragma unroll
        for (int r = 0; r < 4; ++r) {
            p[0][r] = __expf(S[0][r] - FMAX);
            p[1][r] = __expf(S[1][r] - FMAX);
        }
        // 6. P -> wave-private LDS, read back as A-frag
        unsigned short* myP = &sP[wave*512];
        #pragma unroll
        for (int nf = 0; nf < 2; ++nf)
            #pragma unroll
            for (int r = 0; r < 4; ++r) {
                int m = lg*4 + r;
                int jl = nf*16 + l15;
                int pos = m*32 + ((((jl>>3) ^ (m&3))) << 3) + (jl & 7);
                myP[pos] = f2bf(p[nf][r]);
            }
        short8v pa = *(const short8v*)&myP[l15*32 + ((lg ^ (l15 & 3)) << 3)];
        acc_l = __builtin_amdgcn_mfma_f32_16x16x32_bf16(pa, onesf, acc_l,0,0,0);
        // 7. pin V fragments: loads must be complete & in registers HERE
        #pragma unroll
        for (int nf = 0; nf < 12; ++nf)
            asm volatile("" :: "v"(fv[nf]));
        __syncthreads();                          // K/rel reads done

        // ======== phase B: PV(t) from registers ========
        if (t + 1 < 32) { STAGE_K(t + 1); STAGE_REL(t + 1); }
        #pragma unroll
        for (int nf = 0; nf < 12; ++nf)
            acc[nf] = __builtin_amdgcn_mfma_f32_16x16x32_bf16(pa, fv[nf], acc[nf],0,0,0);
        __syncthreads();                          // K/rel(t+1) staged
    }

    // ---- exact wj-pair merge (same fixed max -> plain sums; bf16 scratch
    //      reuses srel: 32*192*2 = 12288 B exactly) ----
    unsigned short* smerge = srel;
    float* mml = (float*)sP;                      // [32] f32 row sums
    if (wj == 1) {
        if (l15 == 0) {
            #pragma unroll
            for (int r = 0; r < 4; ++r)
                mml[wq*16 + lg*4 + r] = acc_l[r];
        }
        #pragma unroll
        for (int nf = 0; nf < 12; ++nf)
            #pragma unroll
            for (int r = 0; r < 4; ++r)
                smerge[(wq*16 + lg*4 + r)*192 + nf*16 + l15] = f2bf(acc[nf][r]);
    }
    __syncthreads();
    if (wj == 0) {
        float inv[4];
        #pragma unroll
        for (int r = 0; r < 4; ++r) {
            int m = wq*16 + lg*4 + r;
            inv[r] = 1.0f / (acc_l[r] + mml[m]);
        }
        #pragma unroll
        for (int nf = 0; nf < 12; ++nf)
            #pragma unroll
            for (int r = 0; r < 4; ++r) {
                int m = wq*16 + lg*4 + r;
                float ov = (acc[nf][r] + bf2f(smerge[m*192 + nf*16 + l15])) * inv[r];
                o[(size_t)(i0 + m)*1536 + h*192 + nf*16 + l15] = f2bf(ov);
            }
    }
}

// ---------------------------------------------------------------------------
extern "C" void kernel_launch(void* const* d_in, const int* in_sizes, int n_in,
                              void* d_out, int out_size, void* d_ws, size_t ws_size,
                              hipStream_t stream)
{
    const float* x     = (const float*)d_in[0];
    const float* Wq    = (const float*)d_in[1];
    const float* Wk    = (const float*)d_in[2];
    const float* Wv    = (const float*)d_in[3];
    const float* Wrel  = (const float*)d_in[4];
    const float* cbias = (const float*)d_in[5];
    const float* pbias = (const float*)d_in[6];
    const float* Wo    = (const float*)d_in[7];
    const float* bo    = (const float*)d_in[8];
    float* out = (float*)d_out;

    char* w = (char*)d_ws;
    auto alloc = [&](size_t bytes) {
        char* p = w; w += (bytes + 255) & ~(size_t)255; return p;
    };
    unsigned short* xhi    = (unsigned short*)alloc((size_t)SEQ*DIMM*2);
    unsigned short* wqkv_h = (unsigned short*)alloc((size_t)2560*DIMM*2);
    unsigned short* wrelt  = (unsigned short*)alloc((size_t)512*NREL*2);
    unsigned short* posb   = (unsigned short*)alloc((size_t)4096*NREL*2);
    unsigned short* qchi   = (unsigned short*)alloc((size_t)8*2048*64*2);
    unsigned short* qpb    = (unsigned short*)alloc((size_t)8*2048*64*2);
    unsigned short* khi    = (unsigned short*)alloc((size_t)8*2048*64*2);
    unsigned short* vt     = (unsigned short*)alloc((size_t)DIMM*SEQ*2);
    unsigned short* relb   = (unsigned short*)alloc((size_t)8*4096*64*2);
    unsigned short* ao     = xhi;              // dead after gemm_qkv
    unsigned short* wot    = wqkv_h;           // dead after gemm_qkv

    // 1. positional embedding (bf16, padded to 4096 rows)
    pos_embed_kernel<<<dim3(512), dim3(256), 0, stream>>>(posb);
    // 2. casts
    cast_bf16<<<dim3(SEQ*DIMM/4/256), 256, 0, stream>>>(
        (const float4*)x, (ushort4v*)xhi, SEQ*DIMM/4);
    castT_kernel<<<dim3(512/32, DIMM/32), 256, 0, stream>>>(
        Wq, wqkv_h, DIMM, 512, 0.125f);
    castT_kernel<<<dim3(512/32, DIMM/32), 256, 0, stream>>>(
        Wk, wqkv_h + (size_t)512*DIMM, DIMM, 512, 1.0f);
    castT_kernel<<<dim3(DIMM/32, DIMM/32), 256, 0, stream>>>(
        Wv, wqkv_h + (size_t)1024*DIMM, DIMM, DIMM, 1.0f);
    castT_kernel<<<dim3(512/32, NREL/32), 256, 0, stream>>>(
        Wrel, wrelt, NREL, 512, 1.0f);
    // 3. fused QKV projection (uniform plain bf16)
    gemm_qkv<<<dim3(2560/64, SEQ/128), 256, 0, stream>>>(
        xhi, wqkv_h, cbias, pbias, qchi, qpb, khi, vt, SEQ, DIMM);
    // 4. rel GEMM -> relb per-head bf16
    gemm_bf16_t<2><<<dim3(512/64, 4096/128), 256, 0, stream>>>(
        posb, wrelt, nullptr, nullptr, relb, 4096, 512, NREL);
    // 5. Wo cast (into wqkv_h; qkv GEMM already consumed it)
    castT_kernel<<<dim3(DIMM/32, DIMM/32), 256, 0, stream>>>(
        Wo, wot, DIMM, DIMM, 1.0f);
    // 6. MFMA flash attention v7
    attn_mfma<<<dim3(HEADS * (SEQ/QB)), 256, 0, stream>>>(
        qchi, qpb, khi, vt, relb, ao);
    // 7. output projection
    gemm_bf16_t<0><<<dim3(DIMM/64, SEQ/128), 256, 0, stream>>>(
        ao, wot, out, bo, nullptr, SEQ, DIMM, DIMM);
}

// Round 13
// 152.771 us; speedup vs baseline: 1.3394x; 1.3394x over previous
//
#include <hip/hip_runtime.h>
#include <math.h>

#define HEADS 8
#define DKEY 64
#define DVAL 192
#define SEQ 2048
#define DIMM 1536
#define NREL 192
#define NB 32
#define TDIST (2*SEQ-1)   // 4095

typedef __attribute__((ext_vector_type(8))) short short8v;   // bf16x8 MFMA frag
typedef __attribute__((ext_vector_type(4))) float f32x4;
typedef __attribute__((ext_vector_type(4))) unsigned short ushort4v;

__device__ __forceinline__ unsigned short f2bf(float f) {
    unsigned int u = __float_as_uint(f);
    u += 0x7FFFu + ((u >> 16) & 1u);          // RNE
    return (unsigned short)(u >> 16);
}
__device__ __forceinline__ float bf2f(unsigned short h) {
    return __uint_as_float(((unsigned int)h) << 16);
}

#define GLOAD16(gp, lp) __builtin_amdgcn_global_load_lds( \
    (const __attribute__((address_space(1))) void*)(gp),  \
    (__attribute__((address_space(3))) void*)(lp), 16, 0, 0)

// ---------------------------------------------------------------------------
// Positional embedding -> bf16 [4096][192]; row 4095 zeroed. All f32.
// ---------------------------------------------------------------------------
__global__ __launch_bounds__(256) void pos_embed_kernel(unsigned short* __restrict__ posb) {
    const int tid = threadIdx.x;
    const int f = tid & 31;
    const int t = blockIdx.x * 8 + (tid >> 5);    // 0..4095
    unsigned short* row = posb + (size_t)t * NREL;
    if (t >= TDIST) {             // pad row: zeros
        row[f] = 0; row[NB+f] = 0; row[2*NB+f] = 0;
        row[96+f] = 0; row[96+NB+f] = 0; row[96+2*NB+f] = 0;
        return;
    }
    float dist = (float)(t - (SEQ - 1));
    float absd = fabsf(dist);
    float sgn  = (dist > 0.0f) ? 1.0f : ((dist < 0.0f) ? -1.0f : 0.0f);
    float hl = exp2f(3.0f + 8.0f * (float)f / 31.0f);
    float e = exp2f(-absd / hl);
    float cw = exp2f((float)(f + 1)) - 1.0f;
    float c = (cw > absd) ? 1.0f : 0.0f;
    // xlogy(conc-1, absd): first arg > 0 always, so absd==0 gives -inf
    float conc = (float)(4 * (f + 1) * (f + 1));
    float rate = ((float)(f + 1)) / 16.0f;
    float lu = (absd > 0.0f)
        ? ((conc - 1.0f) * logf(absd) - rate * absd)
        : -INFINITY;
    float ln = lgammaf(conc) - conc * logf(rate);
    float g = expf(lu - ln) + 1e-8f;
    float gm = g;
    #pragma unroll
    for (int off = 16; off >= 1; off >>= 1)
        gm = fmaxf(gm, __shfl_xor(gm, off, 32));
    g = g / gm;
    row[f]           = f2bf(e);
    row[NB + f]      = f2bf(c);
    row[2*NB + f]    = f2bf(g);
    row[96 + f]      = f2bf(sgn * e);
    row[96 + NB + f] = f2bf(sgn * c);
    row[96 + 2*NB+f] = f2bf(sgn * g);
}

// ---------------------------------------------------------------------------
// x f32 -> bf16 (plain)
// ---------------------------------------------------------------------------
__global__ __launch_bounds__(256) void cast_bf16(
    const float4* __restrict__ in, ushort4v* __restrict__ hi, int n4)
{
    int i = blockIdx.x * 256 + threadIdx.x;
    if (i >= n4) return;
    float4 v = in[i];
    hi[i] = (ushort4v){ f2bf(v.x), f2bf(v.y), f2bf(v.z), f2bf(v.w) };
}

// ---------------------------------------------------------------------------
// W f32 [R][C] -> bf16 transposed [C][R], optionally pre-scaled.
// ---------------------------------------------------------------------------
__global__ __launch_bounds__(256) void castT_kernel(
    const float* __restrict__ in, unsigned short* __restrict__ hiT,
    int R, int C, float scale)
{
    __shared__ float t[32][33];
    int c0 = blockIdx.x * 32, r0 = blockIdx.y * 32;
    int tx = threadIdx.x & 31, ty = threadIdx.x >> 5;
    #pragma unroll
    for (int rr = ty; rr < 32; rr += 8)
        t[rr][tx] = in[(size_t)(r0 + rr) * C + c0 + tx] * scale;
    __syncthreads();
    #pragma unroll
    for (int cc = ty; cc < 32; cc += 8)
        hiT[(size_t)(c0 + cc) * R + r0 + tx] = f2bf(t[tx][cc]);
}

// ---------------------------------------------------------------------------
// bf16 MFMA GEMM, 128x64 tile, double-buffered. 4 waves = 2x2 of (64m x 32n).
//  MODE 0: C f32 [M][N] (+bias)
//  MODE 2: O bf16 per-head [8][4096][64]  (relb; col = h*64+d)
// ---------------------------------------------------------------------------
template<int MODE>
__global__ __launch_bounds__(256) void gemm_bf16_t(
    const unsigned short* __restrict__ A, const unsigned short* __restrict__ Bt,
    float* __restrict__ C, const float* __restrict__ bias,
    unsigned short* __restrict__ O,
    int M, int N, int K)
{
    __shared__ unsigned short A0[128*32], A1[128*32];
    __shared__ unsigned short B0[64*32],  B1[64*32];
    const int tid  = threadIdx.x;
    const int lane = tid & 63;
    const int wave = tid >> 6;
    const int wr = (wave >> 1) * 64, wc = (wave & 1) * 32;
    const int m0 = blockIdx.y * 128, n0 = blockIdx.x * 64;

    const int sr = tid >> 2;
    const int sc = ((tid & 3) ^ ((tid >> 4) & 3)) * 8;
    const unsigned short* gA = A  + (size_t)(m0 + sr) * K + sc;
    const unsigned short* gB = Bt + (size_t)(n0 + sr) * K + sc;

    const int frow = lane & 15;
    const int rchunk = (((lane >> 4) ^ ((frow >> 2) & 3))) * 8;

    f32x4 acc[4][2] = {};
    const int nk = K >> 5;

    auto STAGE = [&](int k0, unsigned short* LA, unsigned short* LB) {
        GLOAD16(gA + k0, LA + (wave*16)*32);
        GLOAD16(gA + k0 + (size_t)64 * K, LA + (64 + wave*16)*32);
        GLOAD16(gB + k0, LB + (wave*16)*32);
    };

    STAGE(0, A0, B0);
    __syncthreads();

    for (int kt = 0; kt < nk; ++kt) {
        const unsigned short* LA = (kt & 1) ? A1 : A0;
        const unsigned short* LB = (kt & 1) ? B1 : B0;
        if (kt + 1 < nk)
            STAGE((kt + 1) << 5, (kt & 1) ? A0 : A1, (kt & 1) ? B0 : B1);
        short8v af[4], bf[2];
        #pragma unroll
        for (int mf = 0; mf < 4; ++mf)
            af[mf] = *(const short8v*)&LA[(wr + mf*16 + frow) * 32 + rchunk];
        #pragma unroll
        for (int nf = 0; nf < 2; ++nf)
            bf[nf] = *(const short8v*)&LB[(wc + nf*16 + frow) * 32 + rchunk];
        #pragma unroll
        for (int mf = 0; mf < 4; ++mf)
            #pragma unroll
            for (int nf = 0; nf < 2; ++nf)
                acc[mf][nf] = __builtin_amdgcn_mfma_f32_16x16x32_bf16(
                    af[mf], bf[nf], acc[mf][nf], 0, 0, 0);
        __syncthreads();
    }

    const int er = ((lane >> 4) << 2);
    const int ec = lane & 15;
    #pragma unroll
    for (int nf = 0; nf < 2; ++nf) {
        const int col = n0 + wc + nf*16 + ec;
        float bv = 0.0f;
        if (MODE == 0 && bias) bv = bias[col];
        #pragma unroll
        for (int mf = 0; mf < 4; ++mf) {
            const int row = m0 + wr + mf*16 + er;
            if (MODE == 0) {
                #pragma unroll
                for (int r = 0; r < 4; ++r)
                    C[(size_t)(row + r) * N + col] = acc[mf][nf][r] + bv;
            } else {
                const int hh = col >> 6, d = col & 63;
                #pragma unroll
                for (int r = 0; r < 4; ++r)
                    O[((size_t)hh*4096 + row + r)*64 + d] = f2bf(acc[mf][nf][r]);
            }
        }
    }
}

// ---------------------------------------------------------------------------
// Fused QKV GEMM — uniform plain bf16 (proven r12). 128x64 tile, grid (40,16).
// Epilogue: q -> qchi(+cbias)/qpb(+pbias), k -> khi, v -> vt^T.
// ---------------------------------------------------------------------------
__global__ __launch_bounds__(256) void gemm_qkv(
    const unsigned short* __restrict__ A, const unsigned short* __restrict__ Bt,
    const float* __restrict__ cbias, const float* __restrict__ pbias,
    unsigned short* __restrict__ qchi, unsigned short* __restrict__ qpb,
    unsigned short* __restrict__ khi,  unsigned short* __restrict__ vt,
    int M, int K)
{
    __shared__ unsigned short A0[128*32], A1[128*32];
    __shared__ unsigned short B0[64*32],  B1[64*32];
    const int tid  = threadIdx.x;
    const int lane = tid & 63;
    const int wave = tid >> 6;
    const int wr = (wave >> 1) * 64, wc = (wave & 1) * 32;
    const int m0 = blockIdx.y * 128, n0 = blockIdx.x * 64;

    const int sr = tid >> 2;
    const int sc = ((tid & 3) ^ ((tid >> 4) & 3)) * 8;
    const unsigned short* gA = A  + (size_t)(m0 + sr) * K + sc;
    const unsigned short* gB = Bt + (size_t)(n0 + sr) * K + sc;

    const int frow = lane & 15;
    const int rchunk = (((lane >> 4) ^ ((frow >> 2) & 3))) * 8;

    f32x4 acc[4][2] = {};
    const int nk = K >> 5;

    auto STAGE = [&](int k0, unsigned short* LA, unsigned short* LB) {
        GLOAD16(gA + k0, LA + (wave*16)*32);
        GLOAD16(gA + k0 + (size_t)64 * K, LA + (64 + wave*16)*32);
        GLOAD16(gB + k0, LB + (wave*16)*32);
    };

    STAGE(0, A0, B0);
    __syncthreads();

    for (int kt = 0; kt < nk; ++kt) {
        const unsigned short* LA = (kt & 1) ? A1 : A0;
        const unsigned short* LB = (kt & 1) ? B1 : B0;
        if (kt + 1 < nk)
            STAGE((kt + 1) << 5, (kt & 1) ? A0 : A1, (kt & 1) ? B0 : B1);
        short8v af[4], bf[2];
        #pragma unroll
        for (int mf = 0; mf < 4; ++mf)
            af[mf] = *(const short8v*)&LA[(wr + mf*16 + frow) * 32 + rchunk];
        #pragma unroll
        for (int nf = 0; nf < 2; ++nf)
            bf[nf] = *(const short8v*)&LB[(wc + nf*16 + frow) * 32 + rchunk];
        #pragma unroll
        for (int mf = 0; mf < 4; ++mf)
            #pragma unroll
            for (int nf = 0; nf < 2; ++nf)
                acc[mf][nf] = __builtin_amdgcn_mfma_f32_16x16x32_bf16(
                    af[mf], bf[nf], acc[mf][nf], 0, 0, 0);
        __syncthreads();
    }

    const int er = ((lane >> 4) << 2);
    const int ec = lane & 15;
    #pragma unroll
    for (int nf = 0; nf < 2; ++nf) {
        const int col = n0 + wc + nf*16 + ec;
        if (col < 1024) {
            const bool isq = col < 512;
            const int hh = (col >> 6) & 7;
            const int d  = col & 63;
            const float cb = isq ? cbias[hh*64 + d] : 0.0f;
            const float pb = isq ? pbias[hh*64 + d] : 0.0f;
            #pragma unroll
            for (int mf = 0; mf < 4; ++mf) {
                const int row = m0 + wr + mf*16 + er;
                #pragma unroll
                for (int r = 0; r < 4; ++r) {
                    const float v = acc[mf][nf][r];
                    const size_t oi = ((size_t)hh*2048 + row + r)*64 + d;
                    if (isq) {
                        qchi[oi] = f2bf(v + cb);
                        qpb[oi]  = f2bf(v + pb);
                    } else {
                        khi[oi] = f2bf(v);
                    }
                }
            }
        } else {
            const int vc = col - 1024;
            #pragma unroll
            for (int mf = 0; mf < 4; ++mf) {
                const int row = m0 + wr + mf*16 + er;
                ushort4v pk;
                #pragma unroll
                for (int r = 0; r < 4; ++r) pk[r] = f2bf(acc[mf][nf][r]);
                *(ushort4v*)(vt + (size_t)vc * M + row) = pk;
            }
        }
    }
}

// ---------------------------------------------------------------------------
// MFMA flash attention v8 — r11's proven staged-V structure + plain-bf16 q
// (4 content MFMA) + ALL staging moved to phase A: V(t) and K/rel(t+1)
// (double-buffered, separate __shared__ arrays) drain at the phase-A barrier
// under the full S-phase; phase B's barrier is load-free. V-in-VGPR is dead
// (r5/r10/r12: 12 frags + acc exceed the register budget every time).
// Fixed-max softmax; exact wj-merge. LDS 68 KB -> 2 blocks/CU.
// ---------------------------------------------------------------------------
#define QB 32
#define KB 64
#define FMAX 24.0f

__global__ __launch_bounds__(256, 2) void attn_mfma(
    const unsigned short* __restrict__ qchi,  // [8][2048][64]
    const unsigned short* __restrict__ qpb,
    const unsigned short* __restrict__ kghi,  // [8][2048][64]
    const unsigned short* __restrict__ vtg,   // [1536][2048] = [8][192][2048]
    const unsigned short* __restrict__ relb,  // [8][4096][64]
    unsigned short* __restrict__ o)           // [2048][1536] bf16
{
    __shared__ __align__(16) unsigned short skhi0[64*64], skhi1[64*64];  // 16 KB
    __shared__ __align__(16) unsigned short srel0[96*64], srel1[96*64];  // 24 KB
    __shared__ __align__(16) unsigned short svt [192*64];                // 24 KB
    __shared__ __align__(16) unsigned short sP  [4*512];                 //  4 KB
    // total 68 KB -> 2 blocks/CU

    const int tid = threadIdx.x;
    const int h  = blockIdx.x & 7;
    const int i0 = (blockIdx.x >> 3) * QB;
    const int lane = tid & 63;
    const int wave = tid >> 6;
    const int wq = wave >> 1, wj = wave & 1;
    const int l15 = lane & 15, lg = lane >> 4;

    const size_t qrow = ((size_t)h*2048 + i0 + wq*16 + l15) * 64;
    short8v fqh[2], fqp[2];
    #pragma unroll
    for (int kh = 0; kh < 2; ++kh) {
        fqh[kh] = *(const short8v*)(qchi + qrow + kh*32 + lg*8);
        fqp[kh] = *(const short8v*)(qpb  + qrow + kh*32 + lg*8);
    }

    short8v onesf;
    #pragma unroll
    for (int j = 0; j < 8; ++j) onesf[j] = (short)0x3F80;

    f32x4 acc[12] = {};
    f32x4 acc_l = {};

    const int offw = wj*32 - wq*16 + 16;

    auto STAGE_KR = [&](int t, unsigned short* dK, unsigned short* dR) {
        const size_t kbase = ((size_t)h*2048 + t*64) * 64;
        #pragma unroll
        for (int it = 0; it < 2; ++it) {
            int u = it*256 + tid; int row = u >> 3; int sch = (u & 7) ^ (row & 7);
            GLOAD16(kghi + kbase + row*64 + sch*8, dK + (it*256 + wave*64)*8);
        }
        const size_t rbase = ((size_t)h*4096 + (t*64 - i0 + 2016)) * 64;
        #pragma unroll
        for (int it = 0; it < 3; ++it) {
            int u = it*256 + tid; int row = u >> 3; int sch = (u & 7) ^ (row & 7);
            GLOAD16(relb + rbase + row*64 + sch*8, dR + (it*256 + wave*64)*8);
        }
    };
    auto STAGE_V = [&](int t) {
        #pragma unroll
        for (int it = 0; it < 6; ++it) {
            int u = it*256 + tid; int n = u >> 3; int sch = (u & 7) ^ (n & 7);
            GLOAD16(vtg + ((size_t)h*192 + n)*2048 + t*64 + sch*8,
                    &svt[(it*256 + wave*64)*8]);
        }
    };

    auto TILE = [&](int t, const unsigned short* curK, const unsigned short* curR,
                    unsigned short* nxtK, unsigned short* nxtR) {
        // ======== phase A: S(t) + ALL staging ========
        // 1. ds_read current K/rel fragments first
        short8v bh[2][2], br[3][2];
        #pragma unroll
        for (int nf = 0; nf < 2; ++nf) {
            int jr = wj*32 + nf*16 + l15;
            #pragma unroll
            for (int kh = 0; kh < 2; ++kh) {
                int c = (kh*4 + lg) ^ (jr & 7);
                bh[nf][kh] = *(const short8v*)&curK[jr*64 + c*8];
            }
        }
        #pragma unroll
        for (int cf = 0; cf < 3; ++cf) {
            int rr = offw + cf*16 + l15;
            #pragma unroll
            for (int kh = 0; kh < 2; ++kh) {
                int c = (kh*4 + lg) ^ (rr & 7);
                br[cf][kh] = *(const short8v*)&curR[rr*64 + c*8];
            }
        }
        // 2. stage V(t) and K/rel(t+1) — drains under the S-phase
        STAGE_V(t);
        if (t + 1 < 32) STAGE_KR(t + 1, nxtK, nxtR);
        // 3. content logits qh.kh (4 MFMA)
        f32x4 sc[2] = {};
        #pragma unroll
        for (int nf = 0; nf < 2; ++nf)
            #pragma unroll
            for (int kh = 0; kh < 2; ++kh)
                sc[nf] = __builtin_amdgcn_mfma_f32_16x16x32_bf16(fqh[kh], bh[nf][kh], sc[nf],0,0,0);
        // rel band logits (6 MFMA)
        f32x4 R[3] = {};
        #pragma unroll
        for (int cf = 0; cf < 3; ++cf)
            #pragma unroll
            for (int kh = 0; kh < 2; ++kh)
                R[cf] = __builtin_amdgcn_mfma_f32_16x16x32_bf16(fqp[kh], br[cf][kh], R[cf],0,0,0);
        // 4. diagonal gather
        float S[2][4];
        #pragma unroll
        for (int r = 0; r < 4; ++r) {
            int m = lg*4 + r;
            int tt2 = l15 + 15 - m;               // 0..30
            int idx = (((lane & 48) | (tt2 & 15))) << 2;
            float g0 = __uint_as_float((unsigned)__builtin_amdgcn_ds_bpermute(idx, (int)__float_as_uint(R[0][r])));
            float g1 = __uint_as_float((unsigned)__builtin_amdgcn_ds_bpermute(idx, (int)__float_as_uint(R[1][r])));
            float g2 = __uint_as_float((unsigned)__builtin_amdgcn_ds_bpermute(idx, (int)__float_as_uint(R[2][r])));
            bool cross = (tt2 >= 16);
            S[0][r] = sc[0][r] + (cross ? g1 : g0);
            S[1][r] = sc[1][r] + (cross ? g2 : g1);
        }
        // 5. fixed-max exponentials
        float p[2][4];
        #pragma unroll
        for (int r = 0; r < 4; ++r) {
            p[0][r] = __expf(S[0][r] - FMAX);
            p[1][r] = __expf(S[1][r] - FMAX);
        }
        // 6. P -> wave-private LDS, read back as A-frag
        unsigned short* myP = &sP[wave*512];
        #pragma unroll
        for (int nf = 0; nf < 2; ++nf)
            #pragma unroll
            for (int r = 0; r < 4; ++r) {
                int m = lg*4 + r;
                int jl = nf*16 + l15;
                int pos = m*32 + ((((jl>>3) ^ (m&3))) << 3) + (jl & 7);
                myP[pos] = f2bf(p[nf][r]);
            }
        short8v pa = *(const short8v*)&myP[l15*32 + ((lg ^ (l15 & 3)) << 3)];
        acc_l = __builtin_amdgcn_mfma_f32_16x16x32_bf16(pa, onesf, acc_l,0,0,0);
        __syncthreads();          // V(t) + K/rel(t+1) staged; cur reads done

        // ======== phase B: PV(t) from LDS V (no staging here) ========
        #pragma unroll
        for (int nf = 0; nf < 12; ++nf) {
            int n = nf*16 + l15;
            int c = (wj*4 + lg) ^ (n & 7);
            short8v bv = *(const short8v*)&svt[n*64 + c*8];
            acc[nf] = __builtin_amdgcn_mfma_f32_16x16x32_bf16(pa, bv, acc[nf],0,0,0);
        }
        __syncthreads();          // V reads done before next tile's V stage
    };

    STAGE_KR(0, skhi0, srel0);
    __syncthreads();

    for (int tt = 0; tt < 32; tt += 2) {
        TILE(tt,     skhi0, srel0, skhi1, srel1);
        TILE(tt + 1, skhi1, srel1, skhi0, srel0);
    }

    // ---- exact wj-pair merge: same fixed max -> plain sums ----
    float* macc = (float*)svt;                    // [32][192] f32 = 24576 B
    float* mml  = (float*)sP;                     // [32] f32 row sums
    if (wj == 1) {
        if (l15 == 0) {
            #pragma unroll
            for (int r = 0; r < 4; ++r)
                mml[wq*16 + lg*4 + r] = acc_l[r];
        }
        #pragma unroll
        for (int nf = 0; nf < 12; ++nf)
            #pragma unroll
            for (int r = 0; r < 4; ++r)
                macc[(wq*16 + lg*4 + r)*192 + nf*16 + l15] = acc[nf][r];
    }
    __syncthreads();
    if (wj == 0) {
        float inv[4];
        #pragma unroll
        for (int r = 0; r < 4; ++r) {
            int m = wq*16 + lg*4 + r;
            inv[r] = 1.0f / (acc_l[r] + mml[m]);
        }
        #pragma unroll
        for (int nf = 0; nf < 12; ++nf)
            #pragma unroll
            for (int r = 0; r < 4; ++r) {
                int m = wq*16 + lg*4 + r;
                float ov = (acc[nf][r] + macc[m*192 + nf*16 + l15]) * inv[r];
                o[(size_t)(i0 + m)*1536 + h*192 + nf*16 + l15] = f2bf(ov);
            }
    }
}

// ---------------------------------------------------------------------------
extern "C" void kernel_launch(void* const* d_in, const int* in_sizes, int n_in,
                              void* d_out, int out_size, void* d_ws, size_t ws_size,
                              hipStream_t stream)
{
    const float* x     = (const float*)d_in[0];
    const float* Wq    = (const float*)d_in[1];
    const float* Wk    = (const float*)d_in[2];
    const float* Wv    = (const float*)d_in[3];
    const float* Wrel  = (const float*)d_in[4];
    const float* cbias = (const float*)d_in[5];
    const float* pbias = (const float*)d_in[6];
    const float* Wo    = (const float*)d_in[7];
    const float* bo    = (const float*)d_in[8];
    float* out = (float*)d_out;

    char* w = (char*)d_ws;
    auto alloc = [&](size_t bytes) {
        char* p = w; w += (bytes + 255) & ~(size_t)255; return p;
    };
    unsigned short* xhi    = (unsigned short*)alloc((size_t)SEQ*DIMM*2);
    unsigned short* wqkv_h = (unsigned short*)alloc((size_t)2560*DIMM*2);
    unsigned short* wrelt  = (unsigned short*)alloc((size_t)512*NREL*2);
    unsigned short* posb   = (unsigned short*)alloc((size_t)4096*NREL*2);
    unsigned short* qchi   = (unsigned short*)alloc((size_t)8*2048*64*2);
    unsigned short* qpb    = (unsigned short*)alloc((size_t)8*2048*64*2);
    unsigned short* khi    = (unsigned short*)alloc((size_t)8*2048*64*2);
    unsigned short* vt     = (unsigned short*)alloc((size_t)DIMM*SEQ*2);
    unsigned short* relb   = (unsigned short*)alloc((size_t)8*4096*64*2);
    unsigned short* ao     = xhi;              // dead after gemm_qkv
    unsigned short* wot    = wqkv_h;           // dead after gemm_qkv

    // 1. positional embedding (bf16, padded to 4096 rows)
    pos_embed_kernel<<<dim3(512), dim3(256), 0, stream>>>(posb);
    // 2. casts
    cast_bf16<<<dim3(SEQ*DIMM/4/256), 256, 0, stream>>>(
        (const float4*)x, (ushort4v*)xhi, SEQ*DIMM/4);
    castT_kernel<<<dim3(512/32, DIMM/32), 256, 0, stream>>>(
        Wq, wqkv_h, DIMM, 512, 0.125f);
    castT_kernel<<<dim3(512/32, DIMM/32), 256, 0, stream>>>(
        Wk, wqkv_h + (size_t)512*DIMM, DIMM, 512, 1.0f);
    castT_kernel<<<dim3(DIMM/32, DIMM/32), 256, 0, stream>>>(
        Wv, wqkv_h + (size_t)1024*DIMM, DIMM, DIMM, 1.0f);
    castT_kernel<<<dim3(512/32, NREL/32), 256, 0, stream>>>(
        Wrel, wrelt, NREL, 512, 1.0f);
    // 3. fused QKV projection (uniform plain bf16)
    gemm_qkv<<<dim3(2560/64, SEQ/128), 256, 0, stream>>>(
        xhi, wqkv_h, cbias, pbias, qchi, qpb, khi, vt, SEQ, DIMM);
    // 4. rel GEMM -> relb per-head bf16
    gemm_bf16_t<2><<<dim3(512/64, 4096/128), 256, 0, stream>>>(
        posb, wrelt, nullptr, nullptr, relb, 4096, 512, NREL);
    // 5. Wo cast (into wqkv_h; qkv GEMM already consumed it)
    castT_kernel<<<dim3(DIMM/32, DIMM/32), 256, 0, stream>>>(
        Wo, wot, DIMM, DIMM, 1.0f);
    // 6. MFMA flash attention v8
    attn_mfma<<<dim3(HEADS * (SEQ/QB)), 256, 0, stream>>>(
        qchi, qpb, khi, vt, relb, ao);
    // 7. output projection
    gemm_bf16_t<0><<<dim3(DIMM/64, SEQ/128), 256, 0, stream>>>(
        ao, wot, out, bo, nullptr, SEQ, DIMM, DIMM);
}

// Round 14
// 120.116 us; speedup vs baseline: 1.7036x; 1.2719x over previous
//
#include <hip/hip_runtime.h>
#include <math.h>

#define HEADS 8
#define DKEY 64
#define DVAL 192
#define SEQ 2048
#define DIMM 1536
#define NREL 192
#define NB 32
#define TDIST (2*SEQ-1)   // 4095

typedef __attribute__((ext_vector_type(8))) short short8v;   // bf16x8 MFMA frag
typedef __attribute__((ext_vector_type(4))) float f32x4;
typedef __attribute__((ext_vector_type(4))) unsigned short ushort4v;

__device__ __forceinline__ unsigned short f2bf(float f) {
    unsigned int u = __float_as_uint(f);
    u += 0x7FFFu + ((u >> 16) & 1u);          // RNE
    return (unsigned short)(u >> 16);
}
__device__ __forceinline__ float bf2f(unsigned short h) {
    return __uint_as_float(((unsigned int)h) << 16);
}

#define GLOAD16(gp, lp) __builtin_amdgcn_global_load_lds( \
    (const __attribute__((address_space(1))) void*)(gp),  \
    (__attribute__((address_space(3))) void*)(lp), 16, 0, 0)

// ---------------------------------------------------------------------------
// prep_kernel: ONE launch for all input preprocessing (6 former launches).
// Jobs by blockIdx.x range (block-uniform branches):
//  [0,3072):    x f32 -> xhi bf16 (flat)
//  [3072,3584): positional embedding -> posb [4096][192] (row 4095 zeroed)
//  [3584,+768): Wq^T * 0.125 -> wqkv_h[0]
//  [+768):      Wk^T -> wqkv_h[512*DIMM]
//  [+2304):     Wv^T -> wqkv_h[1024*DIMM]
//  [+96):       Wrel^T -> wrelt
// ---------------------------------------------------------------------------
__global__ __launch_bounds__(256) void prep_kernel(
    const float* __restrict__ x,  const float* __restrict__ Wq,
    const float* __restrict__ Wk, const float* __restrict__ Wv,
    const float* __restrict__ Wrel,
    unsigned short* __restrict__ xhi, unsigned short* __restrict__ wqkv_h,
    unsigned short* __restrict__ wrelt, unsigned short* __restrict__ posb)
{
    __shared__ float t[32][33];
    int b = blockIdx.x;
    const int tid = threadIdx.x;

    if (b < 3072) {                       // ---- x cast ----
        int i = b * 256 + tid;            // n4 = 786432 = 3072*256
        float4 v = ((const float4*)x)[i];
        ((ushort4v*)xhi)[i] = (ushort4v){f2bf(v.x), f2bf(v.y), f2bf(v.z), f2bf(v.w)};
        return;
    }
    b -= 3072;
    if (b < 512) {                        // ---- positional embedding ----
        const int f = tid & 31;
        const int tt = b * 8 + (tid >> 5);
        unsigned short* row = posb + (size_t)tt * NREL;
        if (tt >= TDIST) {
            row[f] = 0; row[NB+f] = 0; row[2*NB+f] = 0;
            row[96+f] = 0; row[96+NB+f] = 0; row[96+2*NB+f] = 0;
            return;
        }
        float dist = (float)(tt - (SEQ - 1));
        float absd = fabsf(dist);
        float sgn  = (dist > 0.0f) ? 1.0f : ((dist < 0.0f) ? -1.0f : 0.0f);
        float hl = exp2f(3.0f + 8.0f * (float)f / 31.0f);
        float e = exp2f(-absd / hl);
        float cw = exp2f((float)(f + 1)) - 1.0f;
        float c = (cw > absd) ? 1.0f : 0.0f;
        // xlogy(conc-1, absd): first arg > 0 always, so absd==0 gives -inf
        float conc = (float)(4 * (f + 1) * (f + 1));
        float rate = ((float)(f + 1)) / 16.0f;
        float lu = (absd > 0.0f)
            ? ((conc - 1.0f) * logf(absd) - rate * absd)
            : -INFINITY;
        float ln = lgammaf(conc) - conc * logf(rate);
        float g = expf(lu - ln) + 1e-8f;
        float gm = g;
        #pragma unroll
        for (int off = 16; off >= 1; off >>= 1)
            gm = fmaxf(gm, __shfl_xor(gm, off, 32));
        g = g / gm;
        row[f]           = f2bf(e);
        row[NB + f]      = f2bf(c);
        row[2*NB + f]    = f2bf(g);
        row[96 + f]      = f2bf(sgn * e);
        row[96 + NB + f] = f2bf(sgn * c);
        row[96 + 2*NB+f] = f2bf(sgn * g);
        return;
    }
    b -= 512;
    // ---- transpose-cast jobs ----
    const float* src; unsigned short* dst; int R, C; float scale = 1.0f;
    if (b < 768)       { src = Wq;   dst = wqkv_h;                      R = DIMM; C = 512;  scale = 0.125f; }
    else if (b < 1536) { src = Wk;   dst = wqkv_h + (size_t)512*DIMM;   R = DIMM; C = 512;  b -= 768; }
    else if (b < 3840) { src = Wv;   dst = wqkv_h + (size_t)1024*DIMM;  R = DIMM; C = 1536; b -= 1536; }
    else               { src = Wrel; dst = wrelt;                       R = NREL; C = 512;  b -= 3840; }
    const int tilesX = C >> 5;
    const int c0 = (b % tilesX) * 32, r0 = (b / tilesX) * 32;
    const int tx = tid & 31, ty = tid >> 5;
    #pragma unroll
    for (int rr = ty; rr < 32; rr += 8)
        t[rr][tx] = src[(size_t)(r0 + rr) * C + c0 + tx] * scale;
    __syncthreads();
    #pragma unroll
    for (int cc = ty; cc < 32; cc += 8)
        dst[(size_t)(c0 + cc) * R + r0 + tx] = f2bf(t[tx][cc]);
}

// ---------------------------------------------------------------------------
// W f32 [R][C] -> bf16 transposed [C][R] (Wo only; must run after gemm_qkv
// because its destination aliases wqkv_h).
// ---------------------------------------------------------------------------
__global__ __launch_bounds__(256) void castT_kernel(
    const float* __restrict__ in, unsigned short* __restrict__ hiT,
    int R, int C, float scale)
{
    __shared__ float t[32][33];
    int c0 = blockIdx.x * 32, r0 = blockIdx.y * 32;
    int tx = threadIdx.x & 31, ty = threadIdx.x >> 5;
    #pragma unroll
    for (int rr = ty; rr < 32; rr += 8)
        t[rr][tx] = in[(size_t)(r0 + rr) * C + c0 + tx] * scale;
    __syncthreads();
    #pragma unroll
    for (int cc = ty; cc < 32; cc += 8)
        hiT[(size_t)(c0 + cc) * R + r0 + tx] = f2bf(t[tx][cc]);
}

// ---------------------------------------------------------------------------
// bf16 MFMA GEMM, 128x64 tile, BK=64 (half the barrier drains), dbuf.
// 4 waves = 2x2 of (64m x 32n). LDS 48 KB.
//  MODE 0: C f32 [M][N] (+bias)
//  MODE 2: O bf16 per-head [8][4096][64]  (relb; col = h*64+d)
// Swizzle: chunk (3b) ^= row&7 on write (pre-swizzled global src) and read.
// ---------------------------------------------------------------------------
template<int MODE>
__global__ __launch_bounds__(256) void gemm_bf16_t(
    const unsigned short* __restrict__ A, const unsigned short* __restrict__ Bt,
    float* __restrict__ C, const float* __restrict__ bias,
    unsigned short* __restrict__ O,
    int M, int N, int K)
{
    __shared__ unsigned short A0[128*64], A1[128*64];   // 16 KB each
    __shared__ unsigned short B0[64*64],  B1[64*64];    //  8 KB each
    const int tid  = threadIdx.x;
    const int lane = tid & 63;
    const int wave = tid >> 6;
    const int wr = (wave >> 1) * 64, wc = (wave & 1) * 32;
    const int m0 = blockIdx.y * 128, n0 = blockIdx.x * 64;

    const int frow = lane & 15, lg = lane >> 4;
    const int fr7 = frow & 7;

    f32x4 acc[4][2] = {};
    const int nk = K >> 6;

    auto STAGE = [&](int k0, unsigned short* LA, unsigned short* LB) {
        #pragma unroll
        for (int it = 0; it < 4; ++it) {
            int idx = it*256 + tid; int row = idx >> 3; int ch = (idx & 7) ^ (row & 7);
            GLOAD16(A + (size_t)(m0 + row) * K + k0 + ch*8, LA + (it*256 + wave*64)*8);
        }
        #pragma unroll
        for (int it = 0; it < 2; ++it) {
            int idx = it*256 + tid; int row = idx >> 3; int ch = (idx & 7) ^ (row & 7);
            GLOAD16(Bt + (size_t)(n0 + row) * K + k0 + ch*8, LB + (it*256 + wave*64)*8);
        }
    };

    STAGE(0, A0, B0);
    __syncthreads();

    for (int kt = 0; kt < nk; ++kt) {
        const unsigned short* LA = (kt & 1) ? A1 : A0;
        const unsigned short* LB = (kt & 1) ? B1 : B0;
        if (kt + 1 < nk)
            STAGE((kt + 1) << 6, (kt & 1) ? A0 : A1, (kt & 1) ? B0 : B1);
        short8v af[2][4], bf[2][2];
        #pragma unroll
        for (int s = 0; s < 2; ++s) {
            int cs = ((s << 2) | lg) ^ fr7;
            #pragma unroll
            for (int mf = 0; mf < 4; ++mf)
                af[s][mf] = *(const short8v*)&LA[(wr + mf*16 + frow)*64 + cs*8];
            #pragma unroll
            for (int nf = 0; nf < 2; ++nf)
                bf[s][nf] = *(const short8v*)&LB[(wc + nf*16 + frow)*64 + cs*8];
        }
        #pragma unroll
        for (int s = 0; s < 2; ++s)
            #pragma unroll
            for (int mf = 0; mf < 4; ++mf)
                #pragma unroll
                for (int nf = 0; nf < 2; ++nf)
                    acc[mf][nf] = __builtin_amdgcn_mfma_f32_16x16x32_bf16(
                        af[s][mf], bf[s][nf], acc[mf][nf], 0, 0, 0);
        __syncthreads();
    }

    const int er = (lg << 2);
    const int ec = frow;
    #pragma unroll
    for (int nf = 0; nf < 2; ++nf) {
        const int col = n0 + wc + nf*16 + ec;
        float bv = 0.0f;
        if (MODE == 0 && bias) bv = bias[col];
        #pragma unroll
        for (int mf = 0; mf < 4; ++mf) {
            const int row = m0 + wr + mf*16 + er;
            if (MODE == 0) {
                #pragma unroll
                for (int r = 0; r < 4; ++r)
                    C[(size_t)(row + r) * N + col] = acc[mf][nf][r] + bv;
            } else {
                const int hh = col >> 6, d = col & 63;
                #pragma unroll
                for (int r = 0; r < 4; ++r)
                    O[((size_t)hh*4096 + row + r)*64 + d] = f2bf(acc[mf][nf][r]);
            }
        }
    }
}

// ---------------------------------------------------------------------------
// Fused QKV GEMM — uniform plain bf16, 128x64 tile, BK=64, dbuf. Grid (40,16).
// Epilogue: q -> qchi(+cbias)/qpb(+pbias), k -> khi, v -> vt^T.
// ---------------------------------------------------------------------------
__global__ __launch_bounds__(256) void gemm_qkv(
    const unsigned short* __restrict__ A, const unsigned short* __restrict__ Bt,
    const float* __restrict__ cbias, const float* __restrict__ pbias,
    unsigned short* __restrict__ qchi, unsigned short* __restrict__ qpb,
    unsigned short* __restrict__ khi,  unsigned short* __restrict__ vt,
    int M, int K)
{
    __shared__ unsigned short A0[128*64], A1[128*64];
    __shared__ unsigned short B0[64*64],  B1[64*64];
    const int tid  = threadIdx.x;
    const int lane = tid & 63;
    const int wave = tid >> 6;
    const int wr = (wave >> 1) * 64, wc = (wave & 1) * 32;
    const int m0 = blockIdx.y * 128, n0 = blockIdx.x * 64;

    const int frow = lane & 15, lg = lane >> 4;
    const int fr7 = frow & 7;

    f32x4 acc[4][2] = {};
    const int nk = K >> 6;

    auto STAGE = [&](int k0, unsigned short* LA, unsigned short* LB) {
        #pragma unroll
        for (int it = 0; it < 4; ++it) {
            int idx = it*256 + tid; int row = idx >> 3; int ch = (idx & 7) ^ (row & 7);
            GLOAD16(A + (size_t)(m0 + row) * K + k0 + ch*8, LA + (it*256 + wave*64)*8);
        }
        #pragma unroll
        for (int it = 0; it < 2; ++it) {
            int idx = it*256 + tid; int row = idx >> 3; int ch = (idx & 7) ^ (row & 7);
            GLOAD16(Bt + (size_t)(n0 + row) * K + k0 + ch*8, LB + (it*256 + wave*64)*8);
        }
    };

    STAGE(0, A0, B0);
    __syncthreads();

    for (int kt = 0; kt < nk; ++kt) {
        const unsigned short* LA = (kt & 1) ? A1 : A0;
        const unsigned short* LB = (kt & 1) ? B1 : B0;
        if (kt + 1 < nk)
            STAGE((kt + 1) << 6, (kt & 1) ? A0 : A1, (kt & 1) ? B0 : B1);
        short8v af[2][4], bf[2][2];
        #pragma unroll
        for (int s = 0; s < 2; ++s) {
            int cs = ((s << 2) | lg) ^ fr7;
            #pragma unroll
            for (int mf = 0; mf < 4; ++mf)
                af[s][mf] = *(const short8v*)&LA[(wr + mf*16 + frow)*64 + cs*8];
            #pragma unroll
            for (int nf = 0; nf < 2; ++nf)
                bf[s][nf] = *(const short8v*)&LB[(wc + nf*16 + frow)*64 + cs*8];
        }
        #pragma unroll
        for (int s = 0; s < 2; ++s)
            #pragma unroll
            for (int mf = 0; mf < 4; ++mf)
                #pragma unroll
                for (int nf = 0; nf < 2; ++nf)
                    acc[mf][nf] = __builtin_amdgcn_mfma_f32_16x16x32_bf16(
                        af[s][mf], bf[s][nf], acc[mf][nf], 0, 0, 0);
        __syncthreads();
    }

    const int er = (lg << 2);
    const int ec = frow;
    #pragma unroll
    for (int nf = 0; nf < 2; ++nf) {
        const int col = n0 + wc + nf*16 + ec;
        if (col < 1024) {
            const bool isq = col < 512;
            const int hh = (col >> 6) & 7;
            const int d  = col & 63;
            const float cb = isq ? cbias[hh*64 + d] : 0.0f;
            const float pb = isq ? pbias[hh*64 + d] : 0.0f;
            #pragma unroll
            for (int mf = 0; mf < 4; ++mf) {
                const int row = m0 + wr + mf*16 + er;
                #pragma unroll
                for (int r = 0; r < 4; ++r) {
                    const float v = acc[mf][nf][r];
                    const size_t oi = ((size_t)hh*2048 + row + r)*64 + d;
                    if (isq) {
                        qchi[oi] = f2bf(v + cb);
                        qpb[oi]  = f2bf(v + pb);
                    } else {
                        khi[oi] = f2bf(v);
                    }
                }
            }
        } else {
            const int vc = col - 1024;
            #pragma unroll
            for (int mf = 0; mf < 4; ++mf) {
                const int row = m0 + wr + mf*16 + er;
                ushort4v pk;
                #pragma unroll
                for (int r = 0; r < 4; ++r) pk[r] = f2bf(acc[mf][nf][r]);
                *(ushort4v*)(vt + (size_t)vc * M + row) = pk;
            }
        }
    }
}

// ---------------------------------------------------------------------------
// MFMA flash attention v8 + T5 setprio around MFMA clusters (r13 structure:
// staged V, dbuf K/rel, all staging in phase A, load-free phase-B barrier).
// Fixed-max softmax; exact wj-merge. LDS 68 KB -> 2 blocks/CU.
// ---------------------------------------------------------------------------
#define QB 32
#define KB 64
#define FMAX 24.0f

__global__ __launch_bounds__(256, 2) void attn_mfma(
    const unsigned short* __restrict__ qchi,  // [8][2048][64]
    const unsigned short* __restrict__ qpb,
    const unsigned short* __restrict__ kghi,  // [8][2048][64]
    const unsigned short* __restrict__ vtg,   // [1536][2048] = [8][192][2048]
    const unsigned short* __restrict__ relb,  // [8][4096][64]
    unsigned short* __restrict__ o)           // [2048][1536] bf16
{
    __shared__ __align__(16) unsigned short skhi0[64*64], skhi1[64*64];  // 16 KB
    __shared__ __align__(16) unsigned short srel0[96*64], srel1[96*64];  // 24 KB
    __shared__ __align__(16) unsigned short svt [192*64];                // 24 KB
    __shared__ __align__(16) unsigned short sP  [4*512];                 //  4 KB

    const int tid = threadIdx.x;
    const int h  = blockIdx.x & 7;
    const int i0 = (blockIdx.x >> 3) * QB;
    const int lane = tid & 63;
    const int wave = tid >> 6;
    const int wq = wave >> 1, wj = wave & 1;
    const int l15 = lane & 15, lg = lane >> 4;

    const size_t qrow = ((size_t)h*2048 + i0 + wq*16 + l15) * 64;
    short8v fqh[2], fqp[2];
    #pragma unroll
    for (int kh = 0; kh < 2; ++kh) {
        fqh[kh] = *(const short8v*)(qchi + qrow + kh*32 + lg*8);
        fqp[kh] = *(const short8v*)(qpb  + qrow + kh*32 + lg*8);
    }

    short8v onesf;
    #pragma unroll
    for (int j = 0; j < 8; ++j) onesf[j] = (short)0x3F80;

    f32x4 acc[12] = {};
    f32x4 acc_l = {};

    const int offw = wj*32 - wq*16 + 16;

    auto STAGE_KR = [&](int t, unsigned short* dK, unsigned short* dR) {
        const size_t kbase = ((size_t)h*2048 + t*64) * 64;
        #pragma unroll
        for (int it = 0; it < 2; ++it) {
            int u = it*256 + tid; int row = u >> 3; int sch = (u & 7) ^ (row & 7);
            GLOAD16(kghi + kbase + row*64 + sch*8, dK + (it*256 + wave*64)*8);
        }
        const size_t rbase = ((size_t)h*4096 + (t*64 - i0 + 2016)) * 64;
        #pragma unroll
        for (int it = 0; it < 3; ++it) {
            int u = it*256 + tid; int row = u >> 3; int sch = (u & 7) ^ (row & 7);
            GLOAD16(relb + rbase + row*64 + sch*8, dR + (it*256 + wave*64)*8);
        }
    };
    auto STAGE_V = [&](int t) {
        #pragma unroll
        for (int it = 0; it < 6; ++it) {
            int u = it*256 + tid; int n = u >> 3; int sch = (u & 7) ^ (n & 7);
            GLOAD16(vtg + ((size_t)h*192 + n)*2048 + t*64 + sch*8,
                    &svt[(it*256 + wave*64)*8]);
        }
    };

    auto TILE = [&](int t, const unsigned short* curK, const unsigned short* curR,
                    unsigned short* nxtK, unsigned short* nxtR) {
        // ======== phase A: S(t) + ALL staging ========
        short8v bh[2][2], br[3][2];
        #pragma unroll
        for (int nf = 0; nf < 2; ++nf) {
            int jr = wj*32 + nf*16 + l15;
            #pragma unroll
            for (int kh = 0; kh < 2; ++kh) {
                int c = (kh*4 + lg) ^ (jr & 7);
                bh[nf][kh] = *(const short8v*)&curK[jr*64 + c*8];
            }
        }
        #pragma unroll
        for (int cf = 0; cf < 3; ++cf) {
            int rr = offw + cf*16 + l15;
            #pragma unroll
            for (int kh = 0; kh < 2; ++kh) {
                int c = (kh*4 + lg) ^ (rr & 7);
                br[cf][kh] = *(const short8v*)&curR[rr*64 + c*8];
            }
        }
        STAGE_V(t);
        if (t + 1 < 32) STAGE_KR(t + 1, nxtK, nxtR);
        // content + rel logits (10 MFMA) — prioritized cluster
        __builtin_amdgcn_s_setprio(1);
        f32x4 sc[2] = {};
        #pragma unroll
        for (int nf = 0; nf < 2; ++nf)
            #pragma unroll
            for (int kh = 0; kh < 2; ++kh)
                sc[nf] = __builtin_amdgcn_mfma_f32_16x16x32_bf16(fqh[kh], bh[nf][kh], sc[nf],0,0,0);
        f32x4 R[3] = {};
        #pragma unroll
        for (int cf = 0; cf < 3; ++cf)
            #pragma unroll
            for (int kh = 0; kh < 2; ++kh)
                R[cf] = __builtin_amdgcn_mfma_f32_16x16x32_bf16(fqp[kh], br[cf][kh], R[cf],0,0,0);
        __builtin_amdgcn_s_setprio(0);
        // diagonal gather
        float S[2][4];
        #pragma unroll
        for (int r = 0; r < 4; ++r) {
            int m = lg*4 + r;
            int tt2 = l15 + 15 - m;               // 0..30
            int idx = (((lane & 48) | (tt2 & 15))) << 2;
            float g0 = __uint_as_float((unsigned)__builtin_amdgcn_ds_bpermute(idx, (int)__float_as_uint(R[0][r])));
            float g1 = __uint_as_float((unsigned)__builtin_amdgcn_ds_bpermute(idx, (int)__float_as_uint(R[1][r])));
            float g2 = __uint_as_float((unsigned)__builtin_amdgcn_ds_bpermute(idx, (int)__float_as_uint(R[2][r])));
            bool cross = (tt2 >= 16);
            S[0][r] = sc[0][r] + (cross ? g1 : g0);
            S[1][r] = sc[1][r] + (cross ? g2 : g1);
        }
        // fixed-max exponentials
        float p[2][4];
        #pragma unroll
        for (int r = 0; r < 4; ++r) {
            p[0][r] = __expf(S[0][r] - FMAX);
            p[1][r] = __expf(S[1][r] - FMAX);
        }
        // P -> wave-private LDS, read back as A-frag
        unsigned short* myP = &sP[wave*512];
        #pragma unroll
        for (int nf = 0; nf < 2; ++nf)
            #pragma unroll
            for (int r = 0; r < 4; ++r) {
                int m = lg*4 + r;
                int jl = nf*16 + l15;
                int pos = m*32 + ((((jl>>3) ^ (m&3))) << 3) + (jl & 7);
                myP[pos] = f2bf(p[nf][r]);
            }
        short8v pa = *(const short8v*)&myP[l15*32 + ((lg ^ (l15 & 3)) << 3)];
        acc_l = __builtin_amdgcn_mfma_f32_16x16x32_bf16(pa, onesf, acc_l,0,0,0);
        __syncthreads();          // V(t) + K/rel(t+1) staged; cur reads done

        // ======== phase B: PV(t) from LDS V — prioritized cluster ========
        __builtin_amdgcn_s_setprio(1);
        #pragma unroll
        for (int nf = 0; nf < 12; ++nf) {
            int n = nf*16 + l15;
            int c = (wj*4 + lg) ^ (n & 7);
            short8v bv = *(const short8v*)&svt[n*64 + c*8];
            acc[nf] = __builtin_amdgcn_mfma_f32_16x16x32_bf16(pa, bv, acc[nf],0,0,0);
        }
        __builtin_amdgcn_s_setprio(0);
        __syncthreads();          // V reads done before next tile's V stage
    };

    STAGE_KR(0, skhi0, srel0);
    __syncthreads();

    for (int tt = 0; tt < 32; tt += 2) {
        TILE(tt,     skhi0, srel0, skhi1, srel1);
        TILE(tt + 1, skhi1, srel1, skhi0, srel0);
    }

    // ---- exact wj-pair merge: same fixed max -> plain sums ----
    float* macc = (float*)svt;                    // [32][192] f32 = 24576 B
    float* mml  = (float*)sP;                     // [32] f32 row sums
    if (wj == 1) {
        if (l15 == 0) {
            #pragma unroll
            for (int r = 0; r < 4; ++r)
                mml[wq*16 + lg*4 + r] = acc_l[r];
        }
        #pragma unroll
        for (int nf = 0; nf < 12; ++nf)
            #pragma unroll
            for (int r = 0; r < 4; ++r)
                macc[(wq*16 + lg*4 + r)*192 + nf*16 + l15] = acc[nf][r];
    }
    __syncthreads();
    if (wj == 0) {
        float inv[4];
        #pragma unroll
        for (int r = 0; r < 4; ++r) {
            int m = wq*16 + lg*4 + r;
            inv[r] = 1.0f / (acc_l[r] + mml[m]);
        }
        #pragma unroll
        for (int nf = 0; nf < 12; ++nf)
            #pragma unroll
            for (int r = 0; r < 4; ++r) {
                int m = wq*16 + lg*4 + r;
                float ov = (acc[nf][r] + macc[m*192 + nf*16 + l15]) * inv[r];
                o[(size_t)(i0 + m)*1536 + h*192 + nf*16 + l15] = f2bf(ov);
            }
    }
}

// ---------------------------------------------------------------------------
extern "C" void kernel_launch(void* const* d_in, const int* in_sizes, int n_in,
                              void* d_out, int out_size, void* d_ws, size_t ws_size,
                              hipStream_t stream)
{
    const float* x     = (const float*)d_in[0];
    const float* Wq    = (const float*)d_in[1];
    const float* Wk    = (const float*)d_in[2];
    const float* Wv    = (const float*)d_in[3];
    const float* Wrel  = (const float*)d_in[4];
    const float* cbias = (const float*)d_in[5];
    const float* pbias = (const float*)d_in[6];
    const float* Wo    = (const float*)d_in[7];
    const float* bo    = (const float*)d_in[8];
    float* out = (float*)d_out;

    char* w = (char*)d_ws;
    auto alloc = [&](size_t bytes) {
        char* p = w; w += (bytes + 255) & ~(size_t)255; return p;
    };
    unsigned short* xhi    = (unsigned short*)alloc((size_t)SEQ*DIMM*2);
    unsigned short* wqkv_h = (unsigned short*)alloc((size_t)2560*DIMM*2);
    unsigned short* wrelt  = (unsigned short*)alloc((size_t)512*NREL*2);
    unsigned short* posb   = (unsigned short*)alloc((size_t)4096*NREL*2);
    unsigned short* qchi   = (unsigned short*)alloc((size_t)8*2048*64*2);
    unsigned short* qpb    = (unsigned short*)alloc((size_t)8*2048*64*2);
    unsigned short* khi    = (unsigned short*)alloc((size_t)8*2048*64*2);
    unsigned short* vt     = (unsigned short*)alloc((size_t)DIMM*SEQ*2);
    unsigned short* relb   = (unsigned short*)alloc((size_t)8*4096*64*2);
    unsigned short* ao     = xhi;              // dead after gemm_qkv
    unsigned short* wot    = wqkv_h;           // dead after gemm_qkv

    // 1. all preprocessing in ONE launch (x cast, pos embed, 4 weight castTs)
    prep_kernel<<<dim3(7520), 256, 0, stream>>>(
        x, Wq, Wk, Wv, Wrel, xhi, wqkv_h, wrelt, posb);
    // 2. fused QKV projection (uniform plain bf16, BK=64)
    gemm_qkv<<<dim3(2560/64, SEQ/128), 256, 0, stream>>>(
        xhi, wqkv_h, cbias, pbias, qchi, qpb, khi, vt, SEQ, DIMM);
    // 3. rel GEMM -> relb per-head bf16
    gemm_bf16_t<2><<<dim3(512/64, 4096/128), 256, 0, stream>>>(
        posb, wrelt, nullptr, nullptr, relb, 4096, 512, NREL);
    // 4. Wo cast (into wqkv_h; qkv GEMM already consumed it)
    castT_kernel<<<dim3(DIMM/32, DIMM/32), 256, 0, stream>>>(
        Wo, wot, DIMM, DIMM, 1.0f);
    // 5. MFMA flash attention
    attn_mfma<<<dim3(HEADS * (SEQ/QB)), 256, 0, stream>>>(
        qchi, qpb, khi, vt, relb, ao);
    // 6. output projection
    gemm_bf16_t<0><<<dim3(DIMM/64, SEQ/128), 256, 0, stream>>>(
        ao, wot, out, bo, nullptr, SEQ, DIMM, DIMM);
}

// Round 15
// 115.023 us; speedup vs baseline: 1.7790x; 1.0443x over previous
//
#include <hip/hip_runtime.h>
#include <math.h>

#define HEADS 8
#define DKEY 64
#define DVAL 192
#define SEQ 2048
#define DIMM 1536
#define NREL 192
#define NB 32
#define TDIST (2*SEQ-1)   // 4095

typedef __attribute__((ext_vector_type(8))) short short8v;   // bf16x8 MFMA frag
typedef __attribute__((ext_vector_type(4))) float f32x4;
typedef __attribute__((ext_vector_type(4))) unsigned short ushort4v;

__device__ __forceinline__ unsigned short f2bf(float f) {
    unsigned int u = __float_as_uint(f);
    u += 0x7FFFu + ((u >> 16) & 1u);          // RNE
    return (unsigned short)(u >> 16);
}
__device__ __forceinline__ float bf2f(unsigned short h) {
    return __uint_as_float(((unsigned int)h) << 16);
}

#define GLOAD16(gp, lp) __builtin_amdgcn_global_load_lds( \
    (const __attribute__((address_space(1))) void*)(gp),  \
    (__attribute__((address_space(3))) void*)(lp), 16, 0, 0)

// ---------------------------------------------------------------------------
// prep_kernel: ONE launch for ALL input preprocessing (incl. Wo^T now that
// wot has its own buffer). Jobs by blockIdx.x range (block-uniform):
//  [0,3072):      x f32 -> xhi bf16
//  [3072,3584):   positional embedding -> posb [4096][192] (row 4095 zeroed)
//  [3584,+768):   Wq^T * 0.125 -> wqkv_h[0]
//  [+768):        Wk^T -> wqkv_h[512*DIMM]
//  [+2304):       Wv^T -> wqkv_h[1024*DIMM]
//  [+96):         Wrel^T -> wrelt
//  [+2304):       Wo^T -> wot
// total 9824 blocks
// ---------------------------------------------------------------------------
__global__ __launch_bounds__(256) void prep_kernel(
    const float* __restrict__ x,  const float* __restrict__ Wq,
    const float* __restrict__ Wk, const float* __restrict__ Wv,
    const float* __restrict__ Wrel, const float* __restrict__ Wo,
    unsigned short* __restrict__ xhi, unsigned short* __restrict__ wqkv_h,
    unsigned short* __restrict__ wrelt, unsigned short* __restrict__ posb,
    unsigned short* __restrict__ wot)
{
    __shared__ float t[32][33];
    int b = blockIdx.x;
    const int tid = threadIdx.x;

    if (b < 3072) {                       // ---- x cast ----
        int i = b * 256 + tid;            // n4 = 786432 = 3072*256
        float4 v = ((const float4*)x)[i];
        ((ushort4v*)xhi)[i] = (ushort4v){f2bf(v.x), f2bf(v.y), f2bf(v.z), f2bf(v.w)};
        return;
    }
    b -= 3072;
    if (b < 512) {                        // ---- positional embedding ----
        const int f = tid & 31;
        const int tt = b * 8 + (tid >> 5);
        unsigned short* row = posb + (size_t)tt * NREL;
        if (tt >= TDIST) {
            row[f] = 0; row[NB+f] = 0; row[2*NB+f] = 0;
            row[96+f] = 0; row[96+NB+f] = 0; row[96+2*NB+f] = 0;
            return;
        }
        float dist = (float)(tt - (SEQ - 1));
        float absd = fabsf(dist);
        float sgn  = (dist > 0.0f) ? 1.0f : ((dist < 0.0f) ? -1.0f : 0.0f);
        float hl = exp2f(3.0f + 8.0f * (float)f / 31.0f);
        float e = exp2f(-absd / hl);
        float cw = exp2f((float)(f + 1)) - 1.0f;
        float c = (cw > absd) ? 1.0f : 0.0f;
        // xlogy(conc-1, absd): first arg > 0 always, so absd==0 gives -inf
        float conc = (float)(4 * (f + 1) * (f + 1));
        float rate = ((float)(f + 1)) / 16.0f;
        float lu = (absd > 0.0f)
            ? ((conc - 1.0f) * logf(absd) - rate * absd)
            : -INFINITY;
        float ln = lgammaf(conc) - conc * logf(rate);
        float g = expf(lu - ln) + 1e-8f;
        float gm = g;
        #pragma unroll
        for (int off = 16; off >= 1; off >>= 1)
            gm = fmaxf(gm, __shfl_xor(gm, off, 32));
        g = g / gm;
        row[f]           = f2bf(e);
        row[NB + f]      = f2bf(c);
        row[2*NB + f]    = f2bf(g);
        row[96 + f]      = f2bf(sgn * e);
        row[96 + NB + f] = f2bf(sgn * c);
        row[96 + 2*NB+f] = f2bf(sgn * g);
        return;
    }
    b -= 512;
    // ---- transpose-cast jobs ----
    const float* src; unsigned short* dst; int R, C; float scale = 1.0f;
    if (b < 768)       { src = Wq;   dst = wqkv_h;                      R = DIMM; C = 512;  scale = 0.125f; }
    else if (b < 1536) { src = Wk;   dst = wqkv_h + (size_t)512*DIMM;   R = DIMM; C = 512;  b -= 768; }
    else if (b < 3840) { src = Wv;   dst = wqkv_h + (size_t)1024*DIMM;  R = DIMM; C = 1536; b -= 1536; }
    else if (b < 3936) { src = Wrel; dst = wrelt;                       R = NREL; C = 512;  b -= 3840; }
    else               { src = Wo;   dst = wot;                         R = DIMM; C = 1536; b -= 3936; }
    const int tilesX = C >> 5;
    const int c0 = (b % tilesX) * 32, r0 = (b / tilesX) * 32;
    const int tx = tid & 31, ty = tid >> 5;
    #pragma unroll
    for (int rr = ty; rr < 32; rr += 8)
        t[rr][tx] = src[(size_t)(r0 + rr) * C + c0 + tx] * scale;
    __syncthreads();
    #pragma unroll
    for (int cc = ty; cc < 32; cc += 8)
        dst[(size_t)(c0 + cc) * R + r0 + tx] = f2bf(t[tx][cc]);
}

// ---------------------------------------------------------------------------
// gemm_mid: qkv GEMM (640 blocks) + rel GEMM (256 blocks) in ONE launch —
// rel blocks backfill the qkv tail. 128x64 tile, BK=64, dbuf, LDS 48 KB.
//  bx <  640: C = xhi @ wqkv^T (K=1536) -> q/k/v epilogue
//  bx >= 640: C = posb @ wrelt^T (K=192) -> relb per-head epilogue
// ---------------------------------------------------------------------------
__global__ __launch_bounds__(256) void gemm_mid(
    const unsigned short* __restrict__ xhi,  const unsigned short* __restrict__ wqkv,
    const unsigned short* __restrict__ posb, const unsigned short* __restrict__ wrelt,
    const float* __restrict__ cbias, const float* __restrict__ pbias,
    unsigned short* __restrict__ qchi, unsigned short* __restrict__ qpb,
    unsigned short* __restrict__ khi,  unsigned short* __restrict__ vt,
    unsigned short* __restrict__ relb)
{
    __shared__ unsigned short A0[128*64], A1[128*64];   // 16 KB each
    __shared__ unsigned short B0[64*64],  B1[64*64];    //  8 KB each
    const int tid  = threadIdx.x;
    const int lane = tid & 63;
    const int wave = tid >> 6;
    const int wr = (wave >> 1) * 64, wc = (wave & 1) * 32;

    const int bx = blockIdx.x;
    const bool ISQKV = (bx < 640);
    const unsigned short *A, *Bt;
    int m0, n0, K;
    if (ISQKV) { n0 = (bx % 40) * 64;        m0 = (bx / 40) * 128;        A = xhi;  Bt = wqkv;  K = DIMM; }
    else       { int i = bx - 640;
                 n0 = (i % 8) * 64;          m0 = (i / 8) * 128;          A = posb; Bt = wrelt; K = NREL; }
    const int nk = K >> 6;

    const int frow = lane & 15, lg = lane >> 4;
    const int fr7 = frow & 7;

    f32x4 acc[4][2] = {};

    auto STAGE = [&](int k0, unsigned short* LA, unsigned short* LB) {
        #pragma unroll
        for (int it = 0; it < 4; ++it) {
            int idx = it*256 + tid; int row = idx >> 3; int ch = (idx & 7) ^ (row & 7);
            GLOAD16(A + (size_t)(m0 + row) * K + k0 + ch*8, LA + (it*256 + wave*64)*8);
        }
        #pragma unroll
        for (int it = 0; it < 2; ++it) {
            int idx = it*256 + tid; int row = idx >> 3; int ch = (idx & 7) ^ (row & 7);
            GLOAD16(Bt + (size_t)(n0 + row) * K + k0 + ch*8, LB + (it*256 + wave*64)*8);
        }
    };

    STAGE(0, A0, B0);
    __syncthreads();

    for (int kt = 0; kt < nk; ++kt) {
        const unsigned short* LA = (kt & 1) ? A1 : A0;
        const unsigned short* LB = (kt & 1) ? B1 : B0;
        if (kt + 1 < nk)
            STAGE((kt + 1) << 6, (kt & 1) ? A0 : A1, (kt & 1) ? B0 : B1);
        short8v af[2][4], bf[2][2];
        #pragma unroll
        for (int s = 0; s < 2; ++s) {
            int cs = ((s << 2) | lg) ^ fr7;
            #pragma unroll
            for (int mf = 0; mf < 4; ++mf)
                af[s][mf] = *(const short8v*)&LA[(wr + mf*16 + frow)*64 + cs*8];
            #pragma unroll
            for (int nf = 0; nf < 2; ++nf)
                bf[s][nf] = *(const short8v*)&LB[(wc + nf*16 + frow)*64 + cs*8];
        }
        #pragma unroll
        for (int s = 0; s < 2; ++s)
            #pragma unroll
            for (int mf = 0; mf < 4; ++mf)
                #pragma unroll
                for (int nf = 0; nf < 2; ++nf)
                    acc[mf][nf] = __builtin_amdgcn_mfma_f32_16x16x32_bf16(
                        af[s][mf], bf[s][nf], acc[mf][nf], 0, 0, 0);
        __syncthreads();
    }

    const int er = (lg << 2);
    const int ec = frow;
    if (ISQKV) {
        #pragma unroll
        for (int nf = 0; nf < 2; ++nf) {
            const int col = n0 + wc + nf*16 + ec;
            if (col < 1024) {
                const bool isq = col < 512;
                const int hh = (col >> 6) & 7;
                const int d  = col & 63;
                const float cb = isq ? cbias[hh*64 + d] : 0.0f;
                const float pb = isq ? pbias[hh*64 + d] : 0.0f;
                #pragma unroll
                for (int mf = 0; mf < 4; ++mf) {
                    const int row = m0 + wr + mf*16 + er;
                    #pragma unroll
                    for (int r = 0; r < 4; ++r) {
                        const float v = acc[mf][nf][r];
                        const size_t oi = ((size_t)hh*2048 + row + r)*64 + d;
                        if (isq) {
                            qchi[oi] = f2bf(v + cb);
                            qpb[oi]  = f2bf(v + pb);
                        } else {
                            khi[oi] = f2bf(v);
                        }
                    }
                }
            } else {
                const int vc = col - 1024;
                #pragma unroll
                for (int mf = 0; mf < 4; ++mf) {
                    const int row = m0 + wr + mf*16 + er;
                    ushort4v pk;
                    #pragma unroll
                    for (int r = 0; r < 4; ++r) pk[r] = f2bf(acc[mf][nf][r]);
                    *(ushort4v*)(vt + (size_t)vc * SEQ + row) = pk;
                }
            }
        }
    } else {
        #pragma unroll
        for (int nf = 0; nf < 2; ++nf) {
            const int col = n0 + wc + nf*16 + ec;
            const int hh = col >> 6, d = col & 63;
            #pragma unroll
            for (int mf = 0; mf < 4; ++mf) {
                const int row = m0 + wr + mf*16 + er;
                #pragma unroll
                for (int r = 0; r < 4; ++r)
                    relb[((size_t)hh*4096 + row + r)*64 + d] = f2bf(acc[mf][nf][r]);
            }
        }
    }
}

// ---------------------------------------------------------------------------
// bf16 MFMA GEMM, 128x64 tile, BK=64, dbuf (output projection only).
// ---------------------------------------------------------------------------
__global__ __launch_bounds__(256) void gemm_out(
    const unsigned short* __restrict__ A, const unsigned short* __restrict__ Bt,
    float* __restrict__ C, const float* __restrict__ bias,
    int M, int N, int K)
{
    __shared__ unsigned short A0[128*64], A1[128*64];
    __shared__ unsigned short B0[64*64],  B1[64*64];
    const int tid  = threadIdx.x;
    const int lane = tid & 63;
    const int wave = tid >> 6;
    const int wr = (wave >> 1) * 64, wc = (wave & 1) * 32;
    const int m0 = blockIdx.y * 128, n0 = blockIdx.x * 64;

    const int frow = lane & 15, lg = lane >> 4;
    const int fr7 = frow & 7;

    f32x4 acc[4][2] = {};
    const int nk = K >> 6;

    auto STAGE = [&](int k0, unsigned short* LA, unsigned short* LB) {
        #pragma unroll
        for (int it = 0; it < 4; ++it) {
            int idx = it*256 + tid; int row = idx >> 3; int ch = (idx & 7) ^ (row & 7);
            GLOAD16(A + (size_t)(m0 + row) * K + k0 + ch*8, LA + (it*256 + wave*64)*8);
        }
        #pragma unroll
        for (int it = 0; it < 2; ++it) {
            int idx = it*256 + tid; int row = idx >> 3; int ch = (idx & 7) ^ (row & 7);
            GLOAD16(Bt + (size_t)(n0 + row) * K + k0 + ch*8, LB + (it*256 + wave*64)*8);
        }
    };

    STAGE(0, A0, B0);
    __syncthreads();

    for (int kt = 0; kt < nk; ++kt) {
        const unsigned short* LA = (kt & 1) ? A1 : A0;
        const unsigned short* LB = (kt & 1) ? B1 : B0;
        if (kt + 1 < nk)
            STAGE((kt + 1) << 6, (kt & 1) ? A0 : A1, (kt & 1) ? B0 : B1);
        short8v af[2][4], bf[2][2];
        #pragma unroll
        for (int s = 0; s < 2; ++s) {
            int cs = ((s << 2) | lg) ^ fr7;
            #pragma unroll
            for (int mf = 0; mf < 4; ++mf)
                af[s][mf] = *(const short8v*)&LA[(wr + mf*16 + frow)*64 + cs*8];
            #pragma unroll
            for (int nf = 0; nf < 2; ++nf)
                bf[s][nf] = *(const short8v*)&LB[(wc + nf*16 + frow)*64 + cs*8];
        }
        #pragma unroll
        for (int s = 0; s < 2; ++s)
            #pragma unroll
            for (int mf = 0; mf < 4; ++mf)
                #pragma unroll
                for (int nf = 0; nf < 2; ++nf)
                    acc[mf][nf] = __builtin_amdgcn_mfma_f32_16x16x32_bf16(
                        af[s][mf], bf[s][nf], acc[mf][nf], 0, 0, 0);
        __syncthreads();
    }

    const int er = (lg << 2);
    const int ec = frow;
    #pragma unroll
    for (int nf = 0; nf < 2; ++nf) {
        const int col = n0 + wc + nf*16 + ec;
        const float bv = bias ? bias[col] : 0.0f;
        #pragma unroll
        for (int mf = 0; mf < 4; ++mf) {
            const int row = m0 + wr + mf*16 + er;
            #pragma unroll
            for (int r = 0; r < 4; ++r)
                C[(size_t)(row + r) * N + col] = acc[mf][nf][r] + bv;
        }
    }
}

// ---------------------------------------------------------------------------
// MFMA flash attention v8 + setprio (unchanged from round 14).
// ---------------------------------------------------------------------------
#define QB 32
#define KB 64
#define FMAX 24.0f

__global__ __launch_bounds__(256, 2) void attn_mfma(
    const unsigned short* __restrict__ qchi,  // [8][2048][64]
    const unsigned short* __restrict__ qpb,
    const unsigned short* __restrict__ kghi,  // [8][2048][64]
    const unsigned short* __restrict__ vtg,   // [1536][2048] = [8][192][2048]
    const unsigned short* __restrict__ relb,  // [8][4096][64]
    unsigned short* __restrict__ o)           // [2048][1536] bf16
{
    __shared__ __align__(16) unsigned short skhi0[64*64], skhi1[64*64];  // 16 KB
    __shared__ __align__(16) unsigned short srel0[96*64], srel1[96*64];  // 24 KB
    __shared__ __align__(16) unsigned short svt [192*64];                // 24 KB
    __shared__ __align__(16) unsigned short sP  [4*512];                 //  4 KB

    const int tid = threadIdx.x;
    const int h  = blockIdx.x & 7;
    const int i0 = (blockIdx.x >> 3) * QB;
    const int lane = tid & 63;
    const int wave = tid >> 6;
    const int wq = wave >> 1, wj = wave & 1;
    const int l15 = lane & 15, lg = lane >> 4;

    const size_t qrow = ((size_t)h*2048 + i0 + wq*16 + l15) * 64;
    short8v fqh[2], fqp[2];
    #pragma unroll
    for (int kh = 0; kh < 2; ++kh) {
        fqh[kh] = *(const short8v*)(qchi + qrow + kh*32 + lg*8);
        fqp[kh] = *(const short8v*)(qpb  + qrow + kh*32 + lg*8);
    }

    short8v onesf;
    #pragma unroll
    for (int j = 0; j < 8; ++j) onesf[j] = (short)0x3F80;

    f32x4 acc[12] = {};
    f32x4 acc_l = {};

    const int offw = wj*32 - wq*16 + 16;

    auto STAGE_KR = [&](int t, unsigned short* dK, unsigned short* dR) {
        const size_t kbase = ((size_t)h*2048 + t*64) * 64;
        #pragma unroll
        for (int it = 0; it < 2; ++it) {
            int u = it*256 + tid; int row = u >> 3; int sch = (u & 7) ^ (row & 7);
            GLOAD16(kghi + kbase + row*64 + sch*8, dK + (it*256 + wave*64)*8);
        }
        const size_t rbase = ((size_t)h*4096 + (t*64 - i0 + 2016)) * 64;
        #pragma unroll
        for (int it = 0; it < 3; ++it) {
            int u = it*256 + tid; int row = u >> 3; int sch = (u & 7) ^ (row & 7);
            GLOAD16(relb + rbase + row*64 + sch*8, dR + (it*256 + wave*64)*8);
        }
    };
    auto STAGE_V = [&](int t) {
        #pragma unroll
        for (int it = 0; it < 6; ++it) {
            int u = it*256 + tid; int n = u >> 3; int sch = (u & 7) ^ (n & 7);
            GLOAD16(vtg + ((size_t)h*192 + n)*2048 + t*64 + sch*8,
                    &svt[(it*256 + wave*64)*8]);
        }
    };

    auto TILE = [&](int t, const unsigned short* curK, const unsigned short* curR,
                    unsigned short* nxtK, unsigned short* nxtR) {
        // ======== phase A: S(t) + ALL staging ========
        short8v bh[2][2], br[3][2];
        #pragma unroll
        for (int nf = 0; nf < 2; ++nf) {
            int jr = wj*32 + nf*16 + l15;
            #pragma unroll
            for (int kh = 0; kh < 2; ++kh) {
                int c = (kh*4 + lg) ^ (jr & 7);
                bh[nf][kh] = *(const short8v*)&curK[jr*64 + c*8];
            }
        }
        #pragma unroll
        for (int cf = 0; cf < 3; ++cf) {
            int rr = offw + cf*16 + l15;
            #pragma unroll
            for (int kh = 0; kh < 2; ++kh) {
                int c = (kh*4 + lg) ^ (rr & 7);
                br[cf][kh] = *(const short8v*)&curR[rr*64 + c*8];
            }
        }
        STAGE_V(t);
        if (t + 1 < 32) STAGE_KR(t + 1, nxtK, nxtR);
        // content + rel logits (10 MFMA) — prioritized cluster
        __builtin_amdgcn_s_setprio(1);
        f32x4 sc[2] = {};
        #pragma unroll
        for (int nf = 0; nf < 2; ++nf)
            #pragma unroll
            for (int kh = 0; kh < 2; ++kh)
                sc[nf] = __builtin_amdgcn_mfma_f32_16x16x32_bf16(fqh[kh], bh[nf][kh], sc[nf],0,0,0);
        f32x4 R[3] = {};
        #pragma unroll
        for (int cf = 0; cf < 3; ++cf)
            #pragma unroll
            for (int kh = 0; kh < 2; ++kh)
                R[cf] = __builtin_amdgcn_mfma_f32_16x16x32_bf16(fqp[kh], br[cf][kh], R[cf],0,0,0);
        __builtin_amdgcn_s_setprio(0);
        // diagonal gather
        float S[2][4];
        #pragma unroll
        for (int r = 0; r < 4; ++r) {
            int m = lg*4 + r;
            int tt2 = l15 + 15 - m;               // 0..30
            int idx = (((lane & 48) | (tt2 & 15))) << 2;
            float g0 = __uint_as_float((unsigned)__builtin_amdgcn_ds_bpermute(idx, (int)__float_as_uint(R[0][r])));
            float g1 = __uint_as_float((unsigned)__builtin_amdgcn_ds_bpermute(idx, (int)__float_as_uint(R[1][r])));
            float g2 = __uint_as_float((unsigned)__builtin_amdgcn_ds_bpermute(idx, (int)__float_as_uint(R[2][r])));
            bool cross = (tt2 >= 16);
            S[0][r] = sc[0][r] + (cross ? g1 : g0);
            S[1][r] = sc[1][r] + (cross ? g2 : g1);
        }
        // fixed-max exponentials
        float p[2][4];
        #pragma unroll
        for (int r = 0; r < 4; ++r) {
            p[0][r] = __expf(S[0][r] - FMAX);
            p[1][r] = __expf(S[1][r] - FMAX);
        }
        // P -> wave-private LDS, read back as A-frag
        unsigned short* myP = &sP[wave*512];
        #pragma unroll
        for (int nf = 0; nf < 2; ++nf)
            #pragma unroll
            for (int r = 0; r < 4; ++r) {
                int m = lg*4 + r;
                int jl = nf*16 + l15;
                int pos = m*32 + ((((jl>>3) ^ (m&3))) << 3) + (jl & 7);
                myP[pos] = f2bf(p[nf][r]);
            }
        short8v pa = *(const short8v*)&myP[l15*32 + ((lg ^ (l15 & 3)) << 3)];
        acc_l = __builtin_amdgcn_mfma_f32_16x16x32_bf16(pa, onesf, acc_l,0,0,0);
        __syncthreads();          // V(t) + K/rel(t+1) staged; cur reads done

        // ======== phase B: PV(t) from LDS V — prioritized cluster ========
        __builtin_amdgcn_s_setprio(1);
        #pragma unroll
        for (int nf = 0; nf < 12; ++nf) {
            int n = nf*16 + l15;
            int c = (wj*4 + lg) ^ (n & 7);
            short8v bv = *(const short8v*)&svt[n*64 + c*8];
            acc[nf] = __builtin_amdgcn_mfma_f32_16x16x32_bf16(pa, bv, acc[nf],0,0,0);
        }
        __builtin_amdgcn_s_setprio(0);
        __syncthreads();          // V reads done before next tile's V stage
    };

    STAGE_KR(0, skhi0, srel0);
    __syncthreads();

    for (int tt = 0; tt < 32; tt += 2) {
        TILE(tt,     skhi0, srel0, skhi1, srel1);
        TILE(tt + 1, skhi1, srel1, skhi0, srel0);
    }

    // ---- exact wj-pair merge: same fixed max -> plain sums ----
    float* macc = (float*)svt;                    // [32][192] f32 = 24576 B
    float* mml  = (float*)sP;                     // [32] f32 row sums
    if (wj == 1) {
        if (l15 == 0) {
            #pragma unroll
            for (int r = 0; r < 4; ++r)
                mml[wq*16 + lg*4 + r] = acc_l[r];
        }
        #pragma unroll
        for (int nf = 0; nf < 12; ++nf)
            #pragma unroll
            for (int r = 0; r < 4; ++r)
                macc[(wq*16 + lg*4 + r)*192 + nf*16 + l15] = acc[nf][r];
    }
    __syncthreads();
    if (wj == 0) {
        float inv[4];
        #pragma unroll
        for (int r = 0; r < 4; ++r) {
            int m = wq*16 + lg*4 + r;
            inv[r] = 1.0f / (acc_l[r] + mml[m]);
        }
        #pragma unroll
        for (int nf = 0; nf < 12; ++nf)
            #pragma unroll
            for (int r = 0; r < 4; ++r) {
                int m = wq*16 + lg*4 + r;
                float ov = (acc[nf][r] + macc[m*192 + nf*16 + l15]) * inv[r];
                o[(size_t)(i0 + m)*1536 + h*192 + nf*16 + l15] = f2bf(ov);
            }
    }
}

// ---------------------------------------------------------------------------
extern "C" void kernel_launch(void* const* d_in, const int* in_sizes, int n_in,
                              void* d_out, int out_size, void* d_ws, size_t ws_size,
                              hipStream_t stream)
{
    const float* x     = (const float*)d_in[0];
    const float* Wq    = (const float*)d_in[1];
    const float* Wk    = (const float*)d_in[2];
    const float* Wv    = (const float*)d_in[3];
    const float* Wrel  = (const float*)d_in[4];
    const float* cbias = (const float*)d_in[5];
    const float* pbias = (const float*)d_in[6];
    const float* Wo    = (const float*)d_in[7];
    const float* bo    = (const float*)d_in[8];
    float* out = (float*)d_out;

    char* w = (char*)d_ws;
    auto alloc = [&](size_t bytes) {
        char* p = w; w += (bytes + 255) & ~(size_t)255; return p;
    };
    unsigned short* xhi    = (unsigned short*)alloc((size_t)SEQ*DIMM*2);
    unsigned short* wqkv_h = (unsigned short*)alloc((size_t)2560*DIMM*2);
    unsigned short* wot    = (unsigned short*)alloc((size_t)DIMM*DIMM*2);
    unsigned short* wrelt  = (unsigned short*)alloc((size_t)512*NREL*2);
    unsigned short* posb   = (unsigned short*)alloc((size_t)4096*NREL*2);
    unsigned short* qchi   = (unsigned short*)alloc((size_t)8*2048*64*2);
    unsigned short* qpb    = (unsigned short*)alloc((size_t)8*2048*64*2);
    unsigned short* khi    = (unsigned short*)alloc((size_t)8*2048*64*2);
    unsigned short* vt     = (unsigned short*)alloc((size_t)DIMM*SEQ*2);
    unsigned short* relb   = (unsigned short*)alloc((size_t)8*4096*64*2);
    unsigned short* ao     = xhi;              // dead after gemm_mid

    // 1. ALL preprocessing in one launch (x cast, pos embed, 5 weight casts)
    prep_kernel<<<dim3(9824), 256, 0, stream>>>(
        x, Wq, Wk, Wv, Wrel, Wo, xhi, wqkv_h, wrelt, posb, wot);
    // 2. qkv GEMM + rel GEMM in one launch (rel backfills the qkv tail)
    gemm_mid<<<dim3(896), 256, 0, stream>>>(
        xhi, wqkv_h, posb, wrelt, cbias, pbias,
        qchi, qpb, khi, vt, relb);
    // 3. MFMA flash attention
    attn_mfma<<<dim3(HEADS * (SEQ/QB)), 256, 0, stream>>>(
        qchi, qpb, khi, vt, relb, ao);
    // 4. output projection
    gemm_out<<<dim3(DIMM/64, SEQ/128), 256, 0, stream>>>(
        ao, wot, out, bo, SEQ, DIMM, DIMM);
}